// Round 15
// baseline (192.301 us; speedup 1.0000x reference)
//
#include <hip/hip_runtime.h>
#include <hip/hip_bf16.h>
#include <math.h>

#define N_HEAD 16
#define D_HEAD 64
#define T_SEQ 1024
#define BATCH 4
// 1/sqrt(64) * log2(e): Q pre-scaled so scores are in log2 units (exp2 softmax)
#define QSCALE 0.180336879f

typedef float f32x4 __attribute__((ext_vector_type(4)));
typedef short bf16x8 __attribute__((ext_vector_type(8)));
typedef short bf16x4v __attribute__((ext_vector_type(4)));

#define AS1(p) ((const __attribute__((address_space(1))) void*)(p))
#define AS3(p) ((__attribute__((address_space(3))) void*)(p))

// load 8 consecutive bf16 from LDS that are only 8B-aligned (stride 68/72)
__device__ inline bf16x8 ld8(const __hip_bfloat16* p) {
    bf16x4v lo = *(const bf16x4v*)p;
    bf16x4v hi = *(const bf16x4v*)(p + 4);
    return __builtin_shufflevector(lo, hi, 0, 1, 2, 3, 4, 5, 6, 7);
}

// ---------------------------------------------------------------------------
// fused fp32 -> bf16 cast of w, Wqkv (Wo cast folded into flash_attn)
// ---------------------------------------------------------------------------
__global__ __launch_bounds__(256) void cast_all(
    const float* __restrict__ s0, __hip_bfloat16* __restrict__ d0, int n0,
    const float* __restrict__ s1, __hip_bfloat16* __restrict__ d1, int n1) {
    int i = (blockIdx.x * 256 + threadIdx.x) * 8;
    const float* src;
    __hip_bfloat16* dst;
    if (i < n0) { src = s0 + i; dst = d0 + i; }
    else if ((i -= n0) < n1) { src = s1 + i; dst = d1 + i; }
    else return;
    float4 a = *(const float4*)src;
    float4 b = *(const float4*)(src + 4);
    __hip_bfloat16 t[8];
    t[0] = __float2bfloat16(a.x); t[1] = __float2bfloat16(a.y);
    t[2] = __float2bfloat16(a.z); t[3] = __float2bfloat16(a.w);
    t[4] = __float2bfloat16(b.x); t[5] = __float2bfloat16(b.y);
    t[6] = __float2bfloat16(b.z); t[7] = __float2bfloat16(b.w);
    *(uint4*)dst = *(const uint4*)t;
}

// ---------------------------------------------------------------------------
// QKV GEMM (m97 structure, 128x128, BK=32 — round-0 proven form, ~45 us).
// CLOSED after 6 probes: swizzle(r2), BK=64(r2), XCD remap(r3), fp32-direct
// (r4), 8-phase 256^2(r1), 64x128@6blk/CU(r8) all null/negative. Binding
// constraint: staged-bytes fabric BW (~9-10 TB/s L2/L3 level).
// Epilogue: Q scaled by (1/8)*log2e, K, V-transposed with P[0] folded in.
// ---------------------------------------------------------------------------
__global__ __launch_bounds__(256) void qkv_gemm_mfma(
    const __hip_bfloat16* __restrict__ A,   // wb   [4096][1024], row m = t*4+b
    const __hip_bfloat16* __restrict__ B,   // Wqkv [3072][1024]
    const float* __restrict__ P,            // pos_emb [129][64]
    __hip_bfloat16* __restrict__ Qb, __hip_bfloat16* __restrict__ Kb,
    __hip_bfloat16* __restrict__ Vtb) {
    constexpr int Kd = 1024;
    __shared__ __hip_bfloat16 As[128 * 32];
    __shared__ __hip_bfloat16 Bs[128 * 32];
    const int tid = threadIdx.x;
    const int w = tid >> 6, lane = tid & 63;
    const int lanelo = lane & 15, quad = lane >> 4;
    const int wm = (w >> 1) * 64, wn = (w & 1) * 64;
    const int m0 = blockIdx.y * 128, n0 = blockIdx.x * 128;

    const __hip_bfloat16* Ag = A + (size_t)(m0 + w * 16 + (lane >> 2)) * Kd + (lane & 3) * 8;
    const __hip_bfloat16* Bg = B + (size_t)(n0 + w * 16 + (lane >> 2)) * Kd + (lane & 3) * 8;
    __hip_bfloat16* AsW0 = As + w * 16 * 32;
    __hip_bfloat16* AsW1 = As + (64 + w * 16) * 32;
    __hip_bfloat16* BsW0 = Bs + w * 16 * 32;
    __hip_bfloat16* BsW1 = Bs + (64 + w * 16) * 32;

    f32x4 acc[4][4];
#pragma unroll
    for (int i = 0; i < 4; i++)
#pragma unroll
        for (int j = 0; j < 4; j++) acc[i][j] = (f32x4){0.f, 0.f, 0.f, 0.f};

    for (int k0 = 0; k0 < Kd; k0 += 32) {
        __syncthreads();
        __builtin_amdgcn_global_load_lds(AS1(Ag + k0), AS3(AsW0), 16, 0, 0);
        __builtin_amdgcn_global_load_lds(AS1(Ag + 64 * Kd + k0), AS3(AsW1), 16, 0, 0);
        __builtin_amdgcn_global_load_lds(AS1(Bg + k0), AS3(BsW0), 16, 0, 0);
        __builtin_amdgcn_global_load_lds(AS1(Bg + 64 * Kd + k0), AS3(BsW1), 16, 0, 0);
        __syncthreads();
        bf16x8 af[4], bfr[4];
#pragma unroll
        for (int i = 0; i < 4; i++)
            af[i] = *(const bf16x8*)(As + (wm + i * 16 + lanelo) * 32 + quad * 8);
#pragma unroll
        for (int j = 0; j < 4; j++)
            bfr[j] = *(const bf16x8*)(Bs + (wn + j * 16 + lanelo) * 32 + quad * 8);
#pragma unroll
        for (int i = 0; i < 4; i++)
#pragma unroll
            for (int j = 0; j < 4; j++)
                acc[i][j] = __builtin_amdgcn_mfma_f32_16x16x32_bf16(af[i], bfr[j], acc[i][j], 0, 0, 0);
    }

    const int part = n0 >> 10;   // block-uniform: 0=q, 1=k, 2=v
    float p0v[4] = {0.f, 0.f, 0.f, 0.f};
    if (part == 2) {
#pragma unroll
        for (int j = 0; j < 4; j++) p0v[j] = P[j * 16 + lanelo];
    }
#pragma unroll
    for (int i = 0; i < 4; i++)
#pragma unroll
        for (int j = 0; j < 4; j++)
#pragma unroll
            for (int reg = 0; reg < 4; reg++) {
                const int row = m0 + wm + i * 16 + quad * 4 + reg;  // m = t*4+b
                const int col = n0 + wn + j * 16 + lanelo;
                const int t = row >> 2, b = row & 3;
                const int e = col & 1023, h = e >> 6, d = e & 63;
                const float v = acc[i][j][reg];
                if (part == 0)
                    Qb[((size_t)(b * 16 + h) * 1024 + t) * 64 + d] = __float2bfloat16(v * QSCALE);
                else if (part == 1)
                    Kb[((size_t)(b * 16 + h) * 1024 + t) * 64 + d] = __float2bfloat16(v);
                else
                    Vtb[((size_t)(b * 16 + h) * 64 + d) * 1024 + t] = __float2bfloat16(v + p0v[j]);
            }
}

// ---------------------------------------------------------------------------
// GEMM2: out[t,b,n] = sum_e AVb[b*1024+t][e] * Wob[n][e], fp32 out.
// 128x64 tile, BK=64 (16 MFMA per barrier-pair). 24 KB LDS, grid 512 blocks
// (2/CU). 2-way-free XOR swizzle (round-2 version, measured -3.7 us).
// ---------------------------------------------------------------------------
__global__ __launch_bounds__(256) void out_gemm_mfma(
    const __hip_bfloat16* __restrict__ A,
    const __hip_bfloat16* __restrict__ B,
    float* __restrict__ out) {
    constexpr int Kd = 1024;
    __shared__ __hip_bfloat16 As[128 * 64];
    __shared__ __hip_bfloat16 Bs[64 * 64];
    const int tid = threadIdx.x;
    const int w = tid >> 6, lane = tid & 63;
    const int lanelo = lane & 15, quad = lane >> 4;
    const int wm = (w >> 1) * 64, wn = (w & 1) * 32;
    const int m0 = blockIdx.y * 128, n0 = blockIdx.x * 64;

    const int sr = lane >> 3;                        // 0..7
    const int sc = ((lane & 7) ^ sr) * 8;            // swizzled k-col (elems)
    const __hip_bfloat16* Ag = A + (size_t)(m0 + w * 32 + sr) * Kd + sc;   // 4 instrs
    const __hip_bfloat16* Bg = B + (size_t)(n0 + w * 16 + sr) * Kd + sc;   // 2 instrs
    __hip_bfloat16* AsW = As + w * 2048;             // w*32 rows * 64
    __hip_bfloat16* BsW = Bs + w * 1024;             // w*16 rows * 64

    f32x4 acc[4][2];
#pragma unroll
    for (int i = 0; i < 4; i++)
#pragma unroll
        for (int j = 0; j < 2; j++) acc[i][j] = (f32x4){0.f, 0.f, 0.f, 0.f};

    const int cswz = lanelo & 7;

    for (int k0 = 0; k0 < Kd; k0 += 64) {
        __syncthreads();
#pragma unroll
        for (int i = 0; i < 4; i++)
            __builtin_amdgcn_global_load_lds(AS1(Ag + k0 + i * 8 * Kd), AS3(AsW + i * 512), 16, 0, 0);
#pragma unroll
        for (int i = 0; i < 2; i++)
            __builtin_amdgcn_global_load_lds(AS1(Bg + k0 + i * 8 * Kd), AS3(BsW + i * 512), 16, 0, 0);
        __syncthreads();
#pragma unroll
        for (int h = 0; h < 2; h++) {
            const int c16 = (((h * 4 + quad) ^ cswz)) * 8;
            bf16x8 af[4], bfr[2];
#pragma unroll
            for (int i = 0; i < 4; i++)
                af[i] = *(const bf16x8*)(As + (size_t)(wm + i * 16 + lanelo) * 64 + c16);
#pragma unroll
            for (int j = 0; j < 2; j++)
                bfr[j] = *(const bf16x8*)(Bs + (size_t)(wn + j * 16 + lanelo) * 64 + c16);
#pragma unroll
            for (int i = 0; i < 4; i++)
#pragma unroll
                for (int j = 0; j < 2; j++)
                    acc[i][j] = __builtin_amdgcn_mfma_f32_16x16x32_bf16(af[i], bfr[j], acc[i][j], 0, 0, 0);
        }
    }

#pragma unroll
    for (int i = 0; i < 4; i++)
#pragma unroll
        for (int j = 0; j < 2; j++)
#pragma unroll
            for (int reg = 0; reg < 4; reg++) {
                const int row = m0 + wm + i * 16 + quad * 4 + reg;  // m = b*1024+t
                const int col = n0 + wn + j * 16 + lanelo;
                const int b = row >> 10, t = row & 1023;
                out[(size_t)(t * 4 + b) * 1024 + col] = acc[i][j][reg];
            }
}

// ---------------------------------------------------------------------------
// Flash attention, UNPAIRED q-supertiles for occupancy: each block handles
// ONE 64-row q-tile Tq = 15 - blockIdx.y (big-work blocks dispatch first);
// grid (64,16) = 1024 blocks. Single-buffered K/V staging (r13 showed dbuf
// ~null), LDS = 43.3 KB -> 3 blocks/CU (12 waves, was 8 at 2/CU) with 1.33x
// block oversubscription for scheduler backfill of the Tq-imbalance.
// Cost: staged tile-units 100 -> 136 per bh (+36%), cheap since K/V is
// L2-homed (r10 XCD grid: bh = blockIdx.x -> XCD = bh%8, FETCH ~15 MB).
// Wo cast prologue rescaled to 4 elems/thread (1024 blocks x 256 thr x 4 =
// exactly 1M). T5 setprio, exp2 softmax, band-corr epilogue unchanged.
// r11 proved staged LDS + reg-prefetch mandatory (direct-global +35 us).
// ---------------------------------------------------------------------------
__global__ __launch_bounds__(256) void flash_attn(
    const __hip_bfloat16* __restrict__ Qb,
    const __hip_bfloat16* __restrict__ Kb,
    const __hip_bfloat16* __restrict__ Vtb,
    const float* __restrict__ P,
    const float* __restrict__ Wo,
    __hip_bfloat16* __restrict__ Wob,
    __hip_bfloat16* __restrict__ av) {
    __shared__ __hip_bfloat16 Ks[64][72];        // K tile  [klocal][d]
    __shared__ __hip_bfloat16 Vs[64][72];        // V' tile [d][klocal]
    __shared__ __hip_bfloat16 Pl[4][16][68];     // per-wave P tile
    __shared__ __hip_bfloat16 Pband[4][16][68];  // per-wave band
    __shared__ __hip_bfloat16 QPl[4][16][66];    // per-wave Q.P[idx] (log2-scaled)

    const int bh = blockIdx.x;          // 0..63 -> XCD = bh%8 (K/V L2-homed)
    const int Tq = 15 - blockIdx.y;     // big q-tiles dispatch first
    const int b = bh >> 4, h = bh & 15;
    const int tid = threadIdx.x;

    // Wo cast prologue: 4 elems/thread, bijective over 1024x256 threads
    {
        const int gid = (blockIdx.y * 64 + bh) * 256 + tid;   // 0..262143
        const float4 a = *(const float4*)(Wo + (size_t)gid * 4);
        __hip_bfloat16 t[4];
        t[0] = __float2bfloat16(a.x); t[1] = __float2bfloat16(a.y);
        t[2] = __float2bfloat16(a.z); t[3] = __float2bfloat16(a.w);
        *(uint2*)(Wob + (size_t)gid * 4) = *(const uint2*)t;
    }

    const int w = tid >> 6, lane = tid & 63;
    const int lanelo = lane & 15, quad = lane >> 4;
    const size_t qkbase = (size_t)bh * 1024 * 64;
    const size_t vbase  = (size_t)bh * 64 * 1024;

    // staging coordinates: thread stages row sr, element cols sc..sc+15
    const int sr = tid >> 2;
    const int sc = (tid & 3) << 4;
    const __hip_bfloat16* kgb = Kb + qkbase + (size_t)sr * 64 + sc;    // +kt*4096
    const __hip_bfloat16* vgb = Vtb + vbase + (size_t)sr * 1024 + sc;  // +kt*64

    // zero this wave's band
    {
        short* pb = (short*)&Pband[w][0][0];
        for (int i = lane; i < 16 * 68; i += 64) pb[i] = 0;
    }

    // Q A-fragments for this q-tile
    bf16x8 aq0, aq1;
    {
        const __hip_bfloat16* qr = Qb + qkbase + (size_t)(Tq * 64 + w * 16 + lanelo) * 64;
        aq0 = *(const bf16x8*)(qr + quad * 8);
        aq1 = *(const bf16x8*)(qr + 32 + quad * 8);
    }

    // QP[row][i] = Q[row].P[i] via MFMA (Q already log2e-scaled)
#pragma unroll
    for (int jj = 0; jj < 5; jj++) {
        const float* prow = P + (size_t)(jj * 16 + lanelo) * 64 + quad * 8;
        float4 pa = *(const float4*)prow;
        float4 pb = *(const float4*)(prow + 4);
        float4 pc = *(const float4*)(prow + 32);
        float4 pd = *(const float4*)(prow + 36);
        __hip_bfloat16 t0[8], t1[8];
        t0[0] = __float2bfloat16(pa.x); t0[1] = __float2bfloat16(pa.y);
        t0[2] = __float2bfloat16(pa.z); t0[3] = __float2bfloat16(pa.w);
        t0[4] = __float2bfloat16(pb.x); t0[5] = __float2bfloat16(pb.y);
        t0[6] = __float2bfloat16(pb.z); t0[7] = __float2bfloat16(pb.w);
        t1[0] = __float2bfloat16(pc.x); t1[1] = __float2bfloat16(pc.y);
        t1[2] = __float2bfloat16(pc.z); t1[3] = __float2bfloat16(pc.w);
        t1[4] = __float2bfloat16(pd.x); t1[5] = __float2bfloat16(pd.y);
        t1[6] = __float2bfloat16(pd.z); t1[7] = __float2bfloat16(pd.w);
        f32x4 accQ = (f32x4){0.f, 0.f, 0.f, 0.f};
        accQ = __builtin_amdgcn_mfma_f32_16x16x32_bf16(aq0, *(const bf16x8*)t0, accQ, 0, 0, 0);
        accQ = __builtin_amdgcn_mfma_f32_16x16x32_bf16(aq1, *(const bf16x8*)t1, accQ, 0, 0, 0);
#pragma unroll
        for (int reg = 0; reg < 4; reg++)
            QPl[w][quad * 4 + reg][jj * 16 + lanelo] = __float2bfloat16(accQ[reg]);
    }
    float qp0[4];
#pragma unroll
    for (int reg = 0; reg < 4; reg++) qp0[reg] = (float)QPl[w][quad * 4 + reg][0];

    f32x4 o_acc[4], o_l;
#pragma unroll
    for (int dt = 0; dt < 4; dt++) o_acc[dt] = (f32x4){0.f, 0.f, 0.f, 0.f};
    o_l = (f32x4){0.f, 0.f, 0.f, 0.f};
    const short one_bf = 0x3F80;
    const bf16x8 vones = {one_bf, one_bf, one_bf, one_bf, one_bf, one_bf, one_bf, one_bf};

    // prologue: prefetch tile 0 into registers
    uint4 rk0, rk1, rv0, rv1;
    rk0 = *(const uint4*)(kgb);
    rk1 = *(const uint4*)(kgb + 8);
    rv0 = *(const uint4*)(vgb);
    rv1 = *(const uint4*)(vgb + 8);

    for (int kt = 0; kt <= Tq; kt++) {
        __syncthreads();   // all waves done reading previous tile's LDS
        *(uint4*)&Ks[sr][sc]     = rk0;
        *(uint4*)&Ks[sr][sc + 8] = rk1;
        *(uint4*)&Vs[sr][sc]     = rv0;
        *(uint4*)&Vs[sr][sc + 8] = rv1;
        if (kt < Tq) {     // prefetch next tile (latency spans this tile's compute)
            const __hip_bfloat16* kg = kgb + (size_t)(kt + 1) * 4096;
            const __hip_bfloat16* vg = vgb + (size_t)(kt + 1) * 64;
            rk0 = *(const uint4*)(kg);
            rk1 = *(const uint4*)(kg + 8);
            rv0 = *(const uint4*)(vg);
            rv1 = *(const uint4*)(vg + 8);
        }
        __syncthreads();   // tile kt staged

        // S = Q @ K^T
        f32x4 s_acc[4];
        __builtin_amdgcn_s_setprio(1);
#pragma unroll
        for (int ct = 0; ct < 4; ct++) {
            bf16x8 b0 = *(const bf16x8*)&Ks[ct * 16 + lanelo][quad * 8];
            bf16x8 b1 = *(const bf16x8*)&Ks[ct * 16 + lanelo][32 + quad * 8];
            f32x4 acc = (f32x4){0.f, 0.f, 0.f, 0.f};
            acc = __builtin_amdgcn_mfma_f32_16x16x32_bf16(aq0, b0, acc, 0, 0, 0);
            acc = __builtin_amdgcn_mfma_f32_16x16x32_bf16(aq1, b1, acc, 0, 0, 0);
            s_acc[ct] = acc;
        }
        __builtin_amdgcn_s_setprio(0);
        const int q0 = Tq * 64 + w * 16;
        const int obase = q0 - kt * 64;
        if (kt < Tq - 1) {
            // far tile: uniform qp0, no mask
#pragma unroll
            for (int ct = 0; ct < 4; ct++)
#pragma unroll
                for (int reg = 0; reg < 4; reg++) {
                    const float p = __builtin_exp2f(s_acc[ct][reg] + qp0[reg]);
                    Pl[w][quad * 4 + reg][ct * 16 + lanelo] = __float2bfloat16(p);
                }
        } else {
            // near tile: per-element rel idx, mask, band capture
#pragma unroll
            for (int ct = 0; ct < 4; ct++)
#pragma unroll
                for (int reg = 0; reg < 4; reg++) {
                    const int rloc = quad * 4 + reg;
                    const int kl = ct * 16 + lanelo;
                    const int o = obase + rloc - kl;
                    const int idx = (o >= 64 || o < 0) ? 0 : (64 - o);
                    const float add = (float)QPl[w][rloc][idx];
                    const float p = (o < 0) ? 0.f : __builtin_exp2f(s_acc[ct][reg] + add);
                    const __hip_bfloat16 pbv = __float2bfloat16(p);
                    Pl[w][rloc][kl] = pbv;
                    if (o >= 0 && o <= 63) Pband[w][rloc][63 - o] = pbv;
                }
        }
        // O += P @ V' ; l += P @ 1
        __builtin_amdgcn_s_setprio(1);
#pragma unroll
        for (int c = 0; c < 2; c++) {
            bf16x8 ap = ld8(&Pl[w][lanelo][c * 32 + quad * 8]);
#pragma unroll
            for (int dt = 0; dt < 4; dt++) {
                bf16x8 bv = *(const bf16x8*)&Vs[dt * 16 + lanelo][c * 32 + quad * 8];
                o_acc[dt] = __builtin_amdgcn_mfma_f32_16x16x32_bf16(ap, bv, o_acc[dt], 0, 0, 0);
            }
            o_l = __builtin_amdgcn_mfma_f32_16x16x32_bf16(ap, vones, o_l, 0, 0, 0);
        }
        __builtin_amdgcn_s_setprio(0);
    }

    // epilogue: band correction + normalize + store
    {
        const int q0 = Tq * 64 + w * 16;
#pragma unroll
        for (int c = 0; c < 2; c++) {
            bf16x8 ab = ld8(&Pband[w][lanelo][c * 32 + quad * 8]);
#pragma unroll
            for (int dt = 0; dt < 4; dt++) {
                const int d = dt * 16 + lanelo;
                const float p0 = P[d];
                __hip_bfloat16 tb[8];
#pragma unroll
                for (int jj = 0; jj < 8; jj++) {
                    const int kk = c * 32 + quad * 8 + jj;
                    tb[jj] = __float2bfloat16(P[(kk + 1) * 64 + d] - p0);
                }
                o_acc[dt] = __builtin_amdgcn_mfma_f32_16x16x32_bf16(ab, *(const bf16x8*)tb, o_acc[dt], 0, 0, 0);
            }
        }
        float rinv[4];
#pragma unroll
        for (int reg = 0; reg < 4; reg++) rinv[reg] = 1.0f / o_l[reg];
#pragma unroll
        for (int dt = 0; dt < 4; dt++) {
            const int cdim = dt * 16 + lanelo;
#pragma unroll
            for (int reg = 0; reg < 4; reg++) {
                const int q = q0 + quad * 4 + reg;
                av[((size_t)(b * 1024 + q)) * 1024 + h * 64 + cdim] =
                    __float2bfloat16(o_acc[dt][reg] * rinv[reg]);
            }
        }
    }
}

extern "C" void kernel_launch(void* const* d_in, const int* in_sizes, int n_in,
                              void* d_out, int out_size, void* d_ws, size_t ws_size,
                              hipStream_t stream) {
    const float* w       = (const float*)d_in[0];
    // d_in[1] = attn_mask (deterministic causal; recomputed from indices)
    const float* Wqkv    = (const float*)d_in[2];
    const float* pos_emb = (const float*)d_in[3];
    const float* Wo      = (const float*)d_in[4];
    float* out = (float*)d_out;

    const size_t SZ = (size_t)BATCH * N_HEAD * T_SEQ * D_HEAD;  // 4,194,304
    __hip_bfloat16* wb     = (__hip_bfloat16*)d_ws;
    __hip_bfloat16* Wqkvb  = wb + SZ;
    __hip_bfloat16* Wob    = Wqkvb + 3 * 1024 * 1024;
    __hip_bfloat16* Qb     = Wob + 1024 * 1024;
    __hip_bfloat16* Kb     = Qb + SZ;
    __hip_bfloat16* Vtb    = Kb + SZ;
    __hip_bfloat16* AVb    = Vtb + SZ;

    const int n_w = 4096 * 1024, n_wqkv = 3072 * 1024;
    const int n_tot = n_w + n_wqkv;
    cast_all<<<n_tot / 2048, 256, 0, stream>>>(w, wb, n_w, Wqkv, Wqkvb, n_wqkv);

    qkv_gemm_mfma<<<dim3(3072 / 128, 4096 / 128), 256, 0, stream>>>(wb, Wqkvb, pos_emb, Qb, Kb, Vtb);
    // grid (64,16): bh = blockIdx.x -> XCD = bh%8; Tq = 15 - blockIdx.y
    flash_attn<<<dim3(64, 16), 256, 0, stream>>>(Qb, Kb, Vtb, pos_emb, Wo, Wob, AVb);
    out_gemm_mfma<<<dim3(1024 / 64, 4096 / 128), 256, 0, stream>>>(AVb, Wob, out);
}

// Round 16
// 184.995 us; speedup vs baseline: 1.0395x; 1.0395x over previous
//
#include <hip/hip_runtime.h>
#include <hip/hip_bf16.h>
#include <math.h>

#define N_HEAD 16
#define D_HEAD 64
#define T_SEQ 1024
#define BATCH 4
// 1/sqrt(64) * log2(e): Q pre-scaled so scores are in log2 units (exp2 softmax)
#define QSCALE 0.180336879f

typedef float f32x4 __attribute__((ext_vector_type(4)));
typedef short bf16x8 __attribute__((ext_vector_type(8)));
typedef short bf16x4v __attribute__((ext_vector_type(4)));

#define AS1(p) ((const __attribute__((address_space(1))) void*)(p))
#define AS3(p) ((__attribute__((address_space(3))) void*)(p))

// load 8 consecutive bf16 from LDS that are only 8B-aligned (stride 68/72)
__device__ inline bf16x8 ld8(const __hip_bfloat16* p) {
    bf16x4v lo = *(const bf16x4v*)p;
    bf16x4v hi = *(const bf16x4v*)(p + 4);
    return __builtin_shufflevector(lo, hi, 0, 1, 2, 3, 4, 5, 6, 7);
}

// ---------------------------------------------------------------------------
// fused fp32 -> bf16 cast of w, Wqkv (Wo cast folded into flash_attn)
// ---------------------------------------------------------------------------
__global__ __launch_bounds__(256) void cast_all(
    const float* __restrict__ s0, __hip_bfloat16* __restrict__ d0, int n0,
    const float* __restrict__ s1, __hip_bfloat16* __restrict__ d1, int n1) {
    int i = (blockIdx.x * 256 + threadIdx.x) * 8;
    const float* src;
    __hip_bfloat16* dst;
    if (i < n0) { src = s0 + i; dst = d0 + i; }
    else if ((i -= n0) < n1) { src = s1 + i; dst = d1 + i; }
    else return;
    float4 a = *(const float4*)src;
    float4 b = *(const float4*)(src + 4);
    __hip_bfloat16 t[8];
    t[0] = __float2bfloat16(a.x); t[1] = __float2bfloat16(a.y);
    t[2] = __float2bfloat16(a.z); t[3] = __float2bfloat16(a.w);
    t[4] = __float2bfloat16(b.x); t[5] = __float2bfloat16(b.y);
    t[6] = __float2bfloat16(b.z); t[7] = __float2bfloat16(b.w);
    *(uint4*)dst = *(const uint4*)t;
}

// ---------------------------------------------------------------------------
// QKV GEMM (m97 structure, 128x128, BK=32 — round-0 proven form, ~45 us).
// CLOSED after 6 probes: swizzle(r2), BK=64(r2), XCD remap(r3), fp32-direct
// (r4), 8-phase 256^2(r1), 64x128@6blk/CU(r8) all null/negative. Binding
// constraint: staged-bytes fabric BW (~9-10 TB/s L2/L3 level).
// Epilogue: Q scaled by (1/8)*log2e, K, V-transposed with P[0] folded in.
// ---------------------------------------------------------------------------
__global__ __launch_bounds__(256) void qkv_gemm_mfma(
    const __hip_bfloat16* __restrict__ A,   // wb   [4096][1024], row m = t*4+b
    const __hip_bfloat16* __restrict__ B,   // Wqkv [3072][1024]
    const float* __restrict__ P,            // pos_emb [129][64]
    __hip_bfloat16* __restrict__ Qb, __hip_bfloat16* __restrict__ Kb,
    __hip_bfloat16* __restrict__ Vtb) {
    constexpr int Kd = 1024;
    __shared__ __hip_bfloat16 As[128 * 32];
    __shared__ __hip_bfloat16 Bs[128 * 32];
    const int tid = threadIdx.x;
    const int w = tid >> 6, lane = tid & 63;
    const int lanelo = lane & 15, quad = lane >> 4;
    const int wm = (w >> 1) * 64, wn = (w & 1) * 64;
    const int m0 = blockIdx.y * 128, n0 = blockIdx.x * 128;

    const __hip_bfloat16* Ag = A + (size_t)(m0 + w * 16 + (lane >> 2)) * Kd + (lane & 3) * 8;
    const __hip_bfloat16* Bg = B + (size_t)(n0 + w * 16 + (lane >> 2)) * Kd + (lane & 3) * 8;
    __hip_bfloat16* AsW0 = As + w * 16 * 32;
    __hip_bfloat16* AsW1 = As + (64 + w * 16) * 32;
    __hip_bfloat16* BsW0 = Bs + w * 16 * 32;
    __hip_bfloat16* BsW1 = Bs + (64 + w * 16) * 32;

    f32x4 acc[4][4];
#pragma unroll
    for (int i = 0; i < 4; i++)
#pragma unroll
        for (int j = 0; j < 4; j++) acc[i][j] = (f32x4){0.f, 0.f, 0.f, 0.f};

    for (int k0 = 0; k0 < Kd; k0 += 32) {
        __syncthreads();
        __builtin_amdgcn_global_load_lds(AS1(Ag + k0), AS3(AsW0), 16, 0, 0);
        __builtin_amdgcn_global_load_lds(AS1(Ag + 64 * Kd + k0), AS3(AsW1), 16, 0, 0);
        __builtin_amdgcn_global_load_lds(AS1(Bg + k0), AS3(BsW0), 16, 0, 0);
        __builtin_amdgcn_global_load_lds(AS1(Bg + 64 * Kd + k0), AS3(BsW1), 16, 0, 0);
        __syncthreads();
        bf16x8 af[4], bfr[4];
#pragma unroll
        for (int i = 0; i < 4; i++)
            af[i] = *(const bf16x8*)(As + (wm + i * 16 + lanelo) * 32 + quad * 8);
#pragma unroll
        for (int j = 0; j < 4; j++)
            bfr[j] = *(const bf16x8*)(Bs + (wn + j * 16 + lanelo) * 32 + quad * 8);
#pragma unroll
        for (int i = 0; i < 4; i++)
#pragma unroll
            for (int j = 0; j < 4; j++)
                acc[i][j] = __builtin_amdgcn_mfma_f32_16x16x32_bf16(af[i], bfr[j], acc[i][j], 0, 0, 0);
    }

    const int part = n0 >> 10;   // block-uniform: 0=q, 1=k, 2=v
    float p0v[4] = {0.f, 0.f, 0.f, 0.f};
    if (part == 2) {
#pragma unroll
        for (int j = 0; j < 4; j++) p0v[j] = P[j * 16 + lanelo];
    }
#pragma unroll
    for (int i = 0; i < 4; i++)
#pragma unroll
        for (int j = 0; j < 4; j++)
#pragma unroll
            for (int reg = 0; reg < 4; reg++) {
                const int row = m0 + wm + i * 16 + quad * 4 + reg;  // m = t*4+b
                const int col = n0 + wn + j * 16 + lanelo;
                const int t = row >> 2, b = row & 3;
                const int e = col & 1023, h = e >> 6, d = e & 63;
                const float v = acc[i][j][reg];
                if (part == 0)
                    Qb[((size_t)(b * 16 + h) * 1024 + t) * 64 + d] = __float2bfloat16(v * QSCALE);
                else if (part == 1)
                    Kb[((size_t)(b * 16 + h) * 1024 + t) * 64 + d] = __float2bfloat16(v);
                else
                    Vtb[((size_t)(b * 16 + h) * 64 + d) * 1024 + t] = __float2bfloat16(v + p0v[j]);
            }
}

// ---------------------------------------------------------------------------
// GEMM2: out[t,b,n] = sum_e AVb[b*1024+t][e] * Wob[n][e], fp32 out.
// 128x64 tile, BK=64 (16 MFMA per barrier-pair). 24 KB LDS, grid 512 blocks
// (2/CU). 2-way-free XOR swizzle (round-2 version, measured -3.7 us).
// ---------------------------------------------------------------------------
__global__ __launch_bounds__(256) void out_gemm_mfma(
    const __hip_bfloat16* __restrict__ A,
    const __hip_bfloat16* __restrict__ B,
    float* __restrict__ out) {
    constexpr int Kd = 1024;
    __shared__ __hip_bfloat16 As[128 * 64];
    __shared__ __hip_bfloat16 Bs[64 * 64];
    const int tid = threadIdx.x;
    const int w = tid >> 6, lane = tid & 63;
    const int lanelo = lane & 15, quad = lane >> 4;
    const int wm = (w >> 1) * 64, wn = (w & 1) * 32;
    const int m0 = blockIdx.y * 128, n0 = blockIdx.x * 64;

    const int sr = lane >> 3;                        // 0..7
    const int sc = ((lane & 7) ^ sr) * 8;            // swizzled k-col (elems)
    const __hip_bfloat16* Ag = A + (size_t)(m0 + w * 32 + sr) * Kd + sc;   // 4 instrs
    const __hip_bfloat16* Bg = B + (size_t)(n0 + w * 16 + sr) * Kd + sc;   // 2 instrs
    __hip_bfloat16* AsW = As + w * 2048;             // w*32 rows * 64
    __hip_bfloat16* BsW = Bs + w * 1024;             // w*16 rows * 64

    f32x4 acc[4][2];
#pragma unroll
    for (int i = 0; i < 4; i++)
#pragma unroll
        for (int j = 0; j < 2; j++) acc[i][j] = (f32x4){0.f, 0.f, 0.f, 0.f};

    const int cswz = lanelo & 7;

    for (int k0 = 0; k0 < Kd; k0 += 64) {
        __syncthreads();
#pragma unroll
        for (int i = 0; i < 4; i++)
            __builtin_amdgcn_global_load_lds(AS1(Ag + k0 + i * 8 * Kd), AS3(AsW + i * 512), 16, 0, 0);
#pragma unroll
        for (int i = 0; i < 2; i++)
            __builtin_amdgcn_global_load_lds(AS1(Bg + k0 + i * 8 * Kd), AS3(BsW + i * 512), 16, 0, 0);
        __syncthreads();
#pragma unroll
        for (int h = 0; h < 2; h++) {
            const int c16 = (((h * 4 + quad) ^ cswz)) * 8;
            bf16x8 af[4], bfr[2];
#pragma unroll
            for (int i = 0; i < 4; i++)
                af[i] = *(const bf16x8*)(As + (size_t)(wm + i * 16 + lanelo) * 64 + c16);
#pragma unroll
            for (int j = 0; j < 2; j++)
                bfr[j] = *(const bf16x8*)(Bs + (size_t)(wn + j * 16 + lanelo) * 64 + c16);
#pragma unroll
            for (int i = 0; i < 4; i++)
#pragma unroll
                for (int j = 0; j < 2; j++)
                    acc[i][j] = __builtin_amdgcn_mfma_f32_16x16x32_bf16(af[i], bfr[j], acc[i][j], 0, 0, 0);
        }
    }

#pragma unroll
    for (int i = 0; i < 4; i++)
#pragma unroll
        for (int j = 0; j < 2; j++)
#pragma unroll
            for (int reg = 0; reg < 4; reg++) {
                const int row = m0 + wm + i * 16 + quad * 4 + reg;  // m = b*1024+t
                const int col = n0 + wn + j * 16 + lanelo;
                const int b = row >> 10, t = row & 1023;
                out[(size_t)(t * 4 + b) * 1024 + col] = acc[i][j][reg];
            }
}

// ---------------------------------------------------------------------------
// Flash attention (r13 measured best, 185.3 us total): paired q-supertiles
// (TB=15-px big + TS=px small in one k-loop — perfect load balance), staged
// K/V with DOUBLE-BUFFER Ks[2]/Vs[2] (79.9 KB LDS, 2 blocks/CU, ONE barrier
// per tile), XCD-aligned grid (64,8) (bh=blockIdx.x -> XCD=bh%8, K/V L2-homed,
// FETCH 68->15 MB measured r10), Wo cast prologue, T5 setprio. Flash ledger:
// no-staging(r11 --), Pband-global(r9 -), unpaired(r15 -), dbuf(r13 ~+0.5).
// ---------------------------------------------------------------------------
__global__ __launch_bounds__(256) void flash_attn(
    const __hip_bfloat16* __restrict__ Qb,
    const __hip_bfloat16* __restrict__ Kb,
    const __hip_bfloat16* __restrict__ Vtb,
    const float* __restrict__ P,
    const float* __restrict__ Wo,
    __hip_bfloat16* __restrict__ Wob,
    __hip_bfloat16* __restrict__ av) {
    __shared__ __hip_bfloat16 Ks[2][64][72];        // K tiles  [buf][klocal][d]
    __shared__ __hip_bfloat16 Vs[2][64][72];        // V' tiles [buf][d][klocal]
    __shared__ __hip_bfloat16 Pl[4][16][68];        // per-wave P tile (reused by both q-tiles)
    __shared__ __hip_bfloat16 Pband[4][2][16][68];  // per-wave, per-q-tile band
    __shared__ __hip_bfloat16 QPl[4][2][16][66];    // per-wave, per-q-tile Q.P[idx] (log2-scaled)

    const int px = blockIdx.y;        // 0..7  (XCD-aligned relabel, r10)
    const int TB = 15 - px, TS = px;  // big / small supertiles
    const int bh = blockIdx.x;        // 0..63 -> XCD = bh%8
    const int b = bh >> 4, h = bh & 15;
    const int tid = threadIdx.x;

    // Wo cast prologue (for out_gemm; bijective over the 512-block grid)
    {
        const int gid = (bh * 8 + px) * 256 + tid;   // 0..131071
        const float4 a = *(const float4*)(Wo + (size_t)gid * 8);
        const float4 c = *(const float4*)(Wo + (size_t)gid * 8 + 4);
        __hip_bfloat16 t[8];
        t[0] = __float2bfloat16(a.x); t[1] = __float2bfloat16(a.y);
        t[2] = __float2bfloat16(a.z); t[3] = __float2bfloat16(a.w);
        t[4] = __float2bfloat16(c.x); t[5] = __float2bfloat16(c.y);
        t[6] = __float2bfloat16(c.z); t[7] = __float2bfloat16(c.w);
        *(uint4*)(Wob + (size_t)gid * 8) = *(const uint4*)t;
    }

    const int w = tid >> 6, lane = tid & 63;
    const int lanelo = lane & 15, quad = lane >> 4;
    const size_t qkbase = (size_t)bh * 1024 * 64;
    const size_t vbase  = (size_t)bh * 64 * 1024;

    // staging coordinates: thread stages row sr, element cols sc..sc+15
    const int sr = tid >> 2;
    const int sc = (tid & 3) << 4;
    const __hip_bfloat16* kgb = Kb + qkbase + (size_t)sr * 64 + sc;    // +kt*4096
    const __hip_bfloat16* vgb = Vtb + vbase + (size_t)sr * 1024 + sc;  // +kt*64

    // zero this wave's bands
    {
        short* pb = (short*)&Pband[w][0][0][0];
        for (int i = lane; i < 2 * 16 * 68; i += 64) pb[i] = 0;
    }

    // Q A-fragments for both q-tiles
    bf16x8 aqb0, aqb1, aqs0, aqs1;
    {
        const __hip_bfloat16* qrb = Qb + qkbase + (size_t)(TB * 64 + w * 16 + lanelo) * 64;
        aqb0 = *(const bf16x8*)(qrb + quad * 8);
        aqb1 = *(const bf16x8*)(qrb + 32 + quad * 8);
        const __hip_bfloat16* qrs = Qb + qkbase + (size_t)(TS * 64 + w * 16 + lanelo) * 64;
        aqs0 = *(const bf16x8*)(qrs + quad * 8);
        aqs1 = *(const bf16x8*)(qrs + 32 + quad * 8);
    }

    // QP[t][row][i] = Q[row].P[i] via MFMA (Q already log2e-scaled)
#pragma unroll
    for (int jj = 0; jj < 5; jj++) {
        const float* prow = P + (size_t)(jj * 16 + lanelo) * 64 + quad * 8;
        float4 pa = *(const float4*)prow;
        float4 pb = *(const float4*)(prow + 4);
        float4 pc = *(const float4*)(prow + 32);
        float4 pd = *(const float4*)(prow + 36);
        __hip_bfloat16 t0[8], t1[8];
        t0[0] = __float2bfloat16(pa.x); t0[1] = __float2bfloat16(pa.y);
        t0[2] = __float2bfloat16(pa.z); t0[3] = __float2bfloat16(pa.w);
        t0[4] = __float2bfloat16(pb.x); t0[5] = __float2bfloat16(pb.y);
        t0[6] = __float2bfloat16(pb.z); t0[7] = __float2bfloat16(pb.w);
        t1[0] = __float2bfloat16(pc.x); t1[1] = __float2bfloat16(pc.y);
        t1[2] = __float2bfloat16(pc.z); t1[3] = __float2bfloat16(pc.w);
        t1[4] = __float2bfloat16(pd.x); t1[5] = __float2bfloat16(pd.y);
        t1[6] = __float2bfloat16(pd.z); t1[7] = __float2bfloat16(pd.w);
        f32x4 accB = (f32x4){0.f, 0.f, 0.f, 0.f};
        accB = __builtin_amdgcn_mfma_f32_16x16x32_bf16(aqb0, *(const bf16x8*)t0, accB, 0, 0, 0);
        accB = __builtin_amdgcn_mfma_f32_16x16x32_bf16(aqb1, *(const bf16x8*)t1, accB, 0, 0, 0);
        f32x4 accS = (f32x4){0.f, 0.f, 0.f, 0.f};
        accS = __builtin_amdgcn_mfma_f32_16x16x32_bf16(aqs0, *(const bf16x8*)t0, accS, 0, 0, 0);
        accS = __builtin_amdgcn_mfma_f32_16x16x32_bf16(aqs1, *(const bf16x8*)t1, accS, 0, 0, 0);
#pragma unroll
        for (int reg = 0; reg < 4; reg++) {
            QPl[w][0][quad * 4 + reg][jj * 16 + lanelo] = __float2bfloat16(accB[reg]);
            QPl[w][1][quad * 4 + reg][jj * 16 + lanelo] = __float2bfloat16(accS[reg]);
        }
    }
    float qp0b[4], qp0s[4];
#pragma unroll
    for (int reg = 0; reg < 4; reg++) {
        qp0b[reg] = (float)QPl[w][0][quad * 4 + reg][0];
        qp0s[reg] = (float)QPl[w][1][quad * 4 + reg][0];
    }

    f32x4 o_accB[4], o_lB, o_accS[4], o_lS;
#pragma unroll
    for (int dt = 0; dt < 4; dt++) {
        o_accB[dt] = (f32x4){0.f, 0.f, 0.f, 0.f};
        o_accS[dt] = (f32x4){0.f, 0.f, 0.f, 0.f};
    }
    o_lB = (f32x4){0.f, 0.f, 0.f, 0.f};
    o_lS = (f32x4){0.f, 0.f, 0.f, 0.f};
    const short one_bf = 0x3F80;
    const bf16x8 vones = {one_bf, one_bf, one_bf, one_bf, one_bf, one_bf, one_bf, one_bf};

    // per-q-tile score+softmax+PV against the staged tile in buf
    auto do_qtile = [&](int tq, int Tq, const bf16x8& a0, const bf16x8& a1,
                        const float* qp0, f32x4* o_acc, f32x4& o_l, int kt, int buf) {
        // S = Q @ K^T
        f32x4 s_acc[4];
        __builtin_amdgcn_s_setprio(1);
#pragma unroll
        for (int ct = 0; ct < 4; ct++) {
            bf16x8 b0 = *(const bf16x8*)&Ks[buf][ct * 16 + lanelo][quad * 8];
            bf16x8 b1 = *(const bf16x8*)&Ks[buf][ct * 16 + lanelo][32 + quad * 8];
            f32x4 acc = (f32x4){0.f, 0.f, 0.f, 0.f};
            acc = __builtin_amdgcn_mfma_f32_16x16x32_bf16(a0, b0, acc, 0, 0, 0);
            acc = __builtin_amdgcn_mfma_f32_16x16x32_bf16(a1, b1, acc, 0, 0, 0);
            s_acc[ct] = acc;
        }
        __builtin_amdgcn_s_setprio(0);
        const int q0 = Tq * 64 + w * 16;
        const int obase = q0 - kt * 64;
        if (kt < Tq - 1) {
            // far tile: uniform qp0, no mask
#pragma unroll
            for (int ct = 0; ct < 4; ct++)
#pragma unroll
                for (int reg = 0; reg < 4; reg++) {
                    const float p = __builtin_exp2f(s_acc[ct][reg] + qp0[reg]);
                    Pl[w][quad * 4 + reg][ct * 16 + lanelo] = __float2bfloat16(p);
                }
        } else {
            // near tile: per-element rel idx, mask, band capture
#pragma unroll
            for (int ct = 0; ct < 4; ct++)
#pragma unroll
                for (int reg = 0; reg < 4; reg++) {
                    const int rloc = quad * 4 + reg;
                    const int kl = ct * 16 + lanelo;
                    const int o = obase + rloc - kl;
                    const int idx = (o >= 64 || o < 0) ? 0 : (64 - o);
                    const float add = (float)QPl[w][tq][rloc][idx];
                    const float p = (o < 0) ? 0.f : __builtin_exp2f(s_acc[ct][reg] + add);
                    const __hip_bfloat16 pbv = __float2bfloat16(p);
                    Pl[w][rloc][kl] = pbv;
                    if (o >= 0 && o <= 63) Pband[w][tq][rloc][63 - o] = pbv;
                }
        }
        // O += P @ V' ; l += P @ 1
        __builtin_amdgcn_s_setprio(1);
#pragma unroll
        for (int c = 0; c < 2; c++) {
            bf16x8 ap = ld8(&Pl[w][lanelo][c * 32 + quad * 8]);
#pragma unroll
            for (int dt = 0; dt < 4; dt++) {
                bf16x8 bv = *(const bf16x8*)&Vs[buf][dt * 16 + lanelo][c * 32 + quad * 8];
                o_acc[dt] = __builtin_amdgcn_mfma_f32_16x16x32_bf16(ap, bv, o_acc[dt], 0, 0, 0);
            }
            o_l = __builtin_amdgcn_mfma_f32_16x16x32_bf16(ap, vones, o_l, 0, 0, 0);
        }
        __builtin_amdgcn_s_setprio(0);
    };

    // prologue: stage tile 0 into buf 0; prefetch tile 1 into regs
    uint4 rk0, rk1, rv0, rv1;
    rk0 = *(const uint4*)(kgb);
    rk1 = *(const uint4*)(kgb + 8);
    rv0 = *(const uint4*)(vgb);
    rv1 = *(const uint4*)(vgb + 8);
    *(uint4*)&Ks[0][sr][sc]     = rk0;
    *(uint4*)&Ks[0][sr][sc + 8] = rk1;
    *(uint4*)&Vs[0][sr][sc]     = rv0;
    *(uint4*)&Vs[0][sr][sc + 8] = rv1;
    if (TB >= 1) {
        rk0 = *(const uint4*)(kgb + 4096);
        rk1 = *(const uint4*)(kgb + 4096 + 8);
        rv0 = *(const uint4*)(vgb + 64);
        rv1 = *(const uint4*)(vgb + 64 + 8);
    }
    __syncthreads();   // buf0 staged

    for (int kt = 0; kt <= TB; kt++) {
        const int cur = kt & 1;
        if (kt < TB) {
            // stage next tile into the other buffer (overwrites tile kt-1,
            // whose readers finished before the end-of-iter-(kt-1) barrier)
            *(uint4*)&Ks[cur ^ 1][sr][sc]     = rk0;
            *(uint4*)&Ks[cur ^ 1][sr][sc + 8] = rk1;
            *(uint4*)&Vs[cur ^ 1][sr][sc]     = rv0;
            *(uint4*)&Vs[cur ^ 1][sr][sc + 8] = rv1;
            if (kt + 1 < TB) {   // prefetch tile kt+2 (latency spans compute)
                const __hip_bfloat16* kg = kgb + (size_t)(kt + 2) * 4096;
                const __hip_bfloat16* vg = vgb + (size_t)(kt + 2) * 64;
                rk0 = *(const uint4*)(kg);
                rk1 = *(const uint4*)(kg + 8);
                rv0 = *(const uint4*)(vg);
                rv1 = *(const uint4*)(vg + 8);
            }
        }

        do_qtile(0, TB, aqb0, aqb1, qp0b, o_accB, o_lB, kt, cur);
        if (kt <= TS) do_qtile(1, TS, aqs0, aqs1, qp0s, o_accS, o_lS, kt, cur);

        __syncthreads();   // readers of buf[cur] done; buf[cur^1] staged
    }

    // epilogue per q-tile: band correction + normalize + store
#pragma unroll
    for (int tq = 0; tq < 2; tq++) {
        f32x4* o_acc = tq == 0 ? o_accB : o_accS;
        f32x4& o_l   = tq == 0 ? o_lB : o_lS;
        const int q0 = (tq == 0 ? TB : TS) * 64 + w * 16;
#pragma unroll
        for (int c = 0; c < 2; c++) {
            bf16x8 ab = ld8(&Pband[w][tq][lanelo][c * 32 + quad * 8]);
#pragma unroll
            for (int dt = 0; dt < 4; dt++) {
                const int d = dt * 16 + lanelo;
                const float p0 = P[d];
                __hip_bfloat16 tb[8];
#pragma unroll
                for (int jj = 0; jj < 8; jj++) {
                    const int kk = c * 32 + quad * 8 + jj;
                    tb[jj] = __float2bfloat16(P[(kk + 1) * 64 + d] - p0);
                }
                o_acc[dt] = __builtin_amdgcn_mfma_f32_16x16x32_bf16(ab, *(const bf16x8*)tb, o_acc[dt], 0, 0, 0);
            }
        }
        float rinv[4];
#pragma unroll
        for (int reg = 0; reg < 4; reg++) rinv[reg] = 1.0f / o_l[reg];
#pragma unroll
        for (int dt = 0; dt < 4; dt++) {
            const int cdim = dt * 16 + lanelo;
#pragma unroll
            for (int reg = 0; reg < 4; reg++) {
                const int q = q0 + quad * 4 + reg;
                av[((size_t)(b * 1024 + q)) * 1024 + h * 64 + cdim] =
                    __float2bfloat16(o_acc[dt][reg] * rinv[reg]);
            }
        }
    }
}

extern "C" void kernel_launch(void* const* d_in, const int* in_sizes, int n_in,
                              void* d_out, int out_size, void* d_ws, size_t ws_size,
                              hipStream_t stream) {
    const float* w       = (const float*)d_in[0];
    // d_in[1] = attn_mask (deterministic causal; recomputed from indices)
    const float* Wqkv    = (const float*)d_in[2];
    const float* pos_emb = (const float*)d_in[3];
    const float* Wo      = (const float*)d_in[4];
    float* out = (float*)d_out;

    const size_t SZ = (size_t)BATCH * N_HEAD * T_SEQ * D_HEAD;  // 4,194,304
    __hip_bfloat16* wb     = (__hip_bfloat16*)d_ws;
    __hip_bfloat16* Wqkvb  = wb + SZ;
    __hip_bfloat16* Wob    = Wqkvb + 3 * 1024 * 1024;
    __hip_bfloat16* Qb     = Wob + 1024 * 1024;
    __hip_bfloat16* Kb     = Qb + SZ;
    __hip_bfloat16* Vtb    = Kb + SZ;
    __hip_bfloat16* AVb    = Vtb + SZ;

    const int n_w = 4096 * 1024, n_wqkv = 3072 * 1024;
    const int n_tot = n_w + n_wqkv;
    cast_all<<<n_tot / 2048, 256, 0, stream>>>(w, wb, n_w, Wqkv, Wqkvb, n_wqkv);

    qkv_gemm_mfma<<<dim3(3072 / 128, 4096 / 128), 256, 0, stream>>>(wb, Wqkvb, pos_emb, Qb, Kb, Vtb);
    // grid (64,8): bh = blockIdx.x (fast dim) -> XCD = bh%8; K/V L2-homed
    flash_attn<<<dim3(64, 8), 256, 0, stream>>>(Qb, Kb, Vtb, pos_emb, Wo, Wob, AVb);
    out_gemm_mfma<<<dim3(1024 / 64, 4096 / 128), 256, 0, stream>>>(AVb, Wob, out);
}

// Round 17
// 184.268 us; speedup vs baseline: 1.0436x; 1.0039x over previous
//
#include <hip/hip_runtime.h>
#include <hip/hip_bf16.h>
#include <math.h>

#define N_HEAD 16
#define D_HEAD 64
#define T_SEQ 1024
#define BATCH 4
// 1/sqrt(64) * log2(e): Q pre-scaled so scores are in log2 units (exp2 softmax)
#define QSCALE 0.180336879f

typedef float f32x4 __attribute__((ext_vector_type(4)));
typedef short bf16x8 __attribute__((ext_vector_type(8)));
typedef short bf16x4v __attribute__((ext_vector_type(4)));

#define AS1(p) ((const __attribute__((address_space(1))) void*)(p))
#define AS3(p) ((__attribute__((address_space(3))) void*)(p))

// load 8 consecutive bf16 from LDS that are only 8B-aligned (stride 68/72)
__device__ inline bf16x8 ld8(const __hip_bfloat16* p) {
    bf16x4v lo = *(const bf16x4v*)p;
    bf16x4v hi = *(const bf16x4v*)(p + 4);
    return __builtin_shufflevector(lo, hi, 0, 1, 2, 3, 4, 5, 6, 7);
}

// ---------------------------------------------------------------------------
// fused fp32 -> bf16 cast of w, Wqkv (Wo cast folded into flash_attn)
// ---------------------------------------------------------------------------
__global__ __launch_bounds__(256) void cast_all(
    const float* __restrict__ s0, __hip_bfloat16* __restrict__ d0, int n0,
    const float* __restrict__ s1, __hip_bfloat16* __restrict__ d1, int n1) {
    int i = (blockIdx.x * 256 + threadIdx.x) * 8;
    const float* src;
    __hip_bfloat16* dst;
    if (i < n0) { src = s0 + i; dst = d0 + i; }
    else if ((i -= n0) < n1) { src = s1 + i; dst = d1 + i; }
    else return;
    float4 a = *(const float4*)src;
    float4 b = *(const float4*)(src + 4);
    __hip_bfloat16 t[8];
    t[0] = __float2bfloat16(a.x); t[1] = __float2bfloat16(a.y);
    t[2] = __float2bfloat16(a.z); t[3] = __float2bfloat16(a.w);
    t[4] = __float2bfloat16(b.x); t[5] = __float2bfloat16(b.y);
    t[6] = __float2bfloat16(b.z); t[7] = __float2bfloat16(b.w);
    *(uint4*)dst = *(const uint4*)t;
}

// ---------------------------------------------------------------------------
// QKV GEMM (m97 structure, 128x128, BK=32 — round-0 proven form, ~45 us).
// CLOSED after 6 probes: swizzle(r2), BK=64(r2), XCD remap(r3), fp32-direct
// (r4), 8-phase 256^2(r1), 64x128@6blk/CU(r8) all null/negative. Binding
// constraint: staged-bytes fabric BW (~9-10 TB/s L2/L3 level).
// Epilogue: Q scaled by (1/8)*log2e, K, V-transposed with P[0] folded in.
// ---------------------------------------------------------------------------
__global__ __launch_bounds__(256) void qkv_gemm_mfma(
    const __hip_bfloat16* __restrict__ A,   // wb   [4096][1024], row m = t*4+b
    const __hip_bfloat16* __restrict__ B,   // Wqkv [3072][1024]
    const float* __restrict__ P,            // pos_emb [129][64]
    __hip_bfloat16* __restrict__ Qb, __hip_bfloat16* __restrict__ Kb,
    __hip_bfloat16* __restrict__ Vtb) {
    constexpr int Kd = 1024;
    __shared__ __hip_bfloat16 As[128 * 32];
    __shared__ __hip_bfloat16 Bs[128 * 32];
    const int tid = threadIdx.x;
    const int w = tid >> 6, lane = tid & 63;
    const int lanelo = lane & 15, quad = lane >> 4;
    const int wm = (w >> 1) * 64, wn = (w & 1) * 64;
    const int m0 = blockIdx.y * 128, n0 = blockIdx.x * 128;

    const __hip_bfloat16* Ag = A + (size_t)(m0 + w * 16 + (lane >> 2)) * Kd + (lane & 3) * 8;
    const __hip_bfloat16* Bg = B + (size_t)(n0 + w * 16 + (lane >> 2)) * Kd + (lane & 3) * 8;
    __hip_bfloat16* AsW0 = As + w * 16 * 32;
    __hip_bfloat16* AsW1 = As + (64 + w * 16) * 32;
    __hip_bfloat16* BsW0 = Bs + w * 16 * 32;
    __hip_bfloat16* BsW1 = Bs + (64 + w * 16) * 32;

    f32x4 acc[4][4];
#pragma unroll
    for (int i = 0; i < 4; i++)
#pragma unroll
        for (int j = 0; j < 4; j++) acc[i][j] = (f32x4){0.f, 0.f, 0.f, 0.f};

    for (int k0 = 0; k0 < Kd; k0 += 32) {
        __syncthreads();
        __builtin_amdgcn_global_load_lds(AS1(Ag + k0), AS3(AsW0), 16, 0, 0);
        __builtin_amdgcn_global_load_lds(AS1(Ag + 64 * Kd + k0), AS3(AsW1), 16, 0, 0);
        __builtin_amdgcn_global_load_lds(AS1(Bg + k0), AS3(BsW0), 16, 0, 0);
        __builtin_amdgcn_global_load_lds(AS1(Bg + 64 * Kd + k0), AS3(BsW1), 16, 0, 0);
        __syncthreads();
        bf16x8 af[4], bfr[4];
#pragma unroll
        for (int i = 0; i < 4; i++)
            af[i] = *(const bf16x8*)(As + (wm + i * 16 + lanelo) * 32 + quad * 8);
#pragma unroll
        for (int j = 0; j < 4; j++)
            bfr[j] = *(const bf16x8*)(Bs + (wn + j * 16 + lanelo) * 32 + quad * 8);
#pragma unroll
        for (int i = 0; i < 4; i++)
#pragma unroll
            for (int j = 0; j < 4; j++)
                acc[i][j] = __builtin_amdgcn_mfma_f32_16x16x32_bf16(af[i], bfr[j], acc[i][j], 0, 0, 0);
    }

    const int part = n0 >> 10;   // block-uniform: 0=q, 1=k, 2=v
    float p0v[4] = {0.f, 0.f, 0.f, 0.f};
    if (part == 2) {
#pragma unroll
        for (int j = 0; j < 4; j++) p0v[j] = P[j * 16 + lanelo];
    }
#pragma unroll
    for (int i = 0; i < 4; i++)
#pragma unroll
        for (int j = 0; j < 4; j++)
#pragma unroll
            for (int reg = 0; reg < 4; reg++) {
                const int row = m0 + wm + i * 16 + quad * 4 + reg;  // m = t*4+b
                const int col = n0 + wn + j * 16 + lanelo;
                const int t = row >> 2, b = row & 3;
                const int e = col & 1023, h = e >> 6, d = e & 63;
                const float v = acc[i][j][reg];
                if (part == 0)
                    Qb[((size_t)(b * 16 + h) * 1024 + t) * 64 + d] = __float2bfloat16(v * QSCALE);
                else if (part == 1)
                    Kb[((size_t)(b * 16 + h) * 1024 + t) * 64 + d] = __float2bfloat16(v);
                else
                    Vtb[((size_t)(b * 16 + h) * 64 + d) * 1024 + t] = __float2bfloat16(v + p0v[j]);
            }
}

// ---------------------------------------------------------------------------
// GEMM2: out[t,b,n] = sum_e AVb[b*1024+t][e] * Wob[n][e], fp32 out.
// 128x64 tile, BK=64, 24 KB LDS, 512 blocks (2/CU), r2 XOR swizzle.
// R17: XCD-HOMED grid — launched (32,16) with m0 = blockIdx.x*128 (fast dim)
// so XCD = (m0/128)%8: each XCD owns 4 A-panels (1 MB) x all Wob (2 MB)
// = 3 MB < 4 MB L2; A reused 16x from L2 (was: every XCD streamed all
// 8.4 MB of A with only 2x reuse). Same mechanism as flash's r10 win.
// ---------------------------------------------------------------------------
__global__ __launch_bounds__(256) void out_gemm_mfma(
    const __hip_bfloat16* __restrict__ A,
    const __hip_bfloat16* __restrict__ B,
    float* __restrict__ out) {
    constexpr int Kd = 1024;
    __shared__ __hip_bfloat16 As[128 * 64];
    __shared__ __hip_bfloat16 Bs[64 * 64];
    const int tid = threadIdx.x;
    const int w = tid >> 6, lane = tid & 63;
    const int lanelo = lane & 15, quad = lane >> 4;
    const int wm = (w >> 1) * 64, wn = (w & 1) * 32;
    const int m0 = blockIdx.x * 128, n0 = blockIdx.y * 64;   // XCD = (m0/128)%8

    const int sr = lane >> 3;                        // 0..7
    const int sc = ((lane & 7) ^ sr) * 8;            // swizzled k-col (elems)
    const __hip_bfloat16* Ag = A + (size_t)(m0 + w * 32 + sr) * Kd + sc;   // 4 instrs
    const __hip_bfloat16* Bg = B + (size_t)(n0 + w * 16 + sr) * Kd + sc;   // 2 instrs
    __hip_bfloat16* AsW = As + w * 2048;             // w*32 rows * 64
    __hip_bfloat16* BsW = Bs + w * 1024;             // w*16 rows * 64

    f32x4 acc[4][2];
#pragma unroll
    for (int i = 0; i < 4; i++)
#pragma unroll
        for (int j = 0; j < 2; j++) acc[i][j] = (f32x4){0.f, 0.f, 0.f, 0.f};

    const int cswz = lanelo & 7;

    for (int k0 = 0; k0 < Kd; k0 += 64) {
        __syncthreads();
#pragma unroll
        for (int i = 0; i < 4; i++)
            __builtin_amdgcn_global_load_lds(AS1(Ag + k0 + i * 8 * Kd), AS3(AsW + i * 512), 16, 0, 0);
#pragma unroll
        for (int i = 0; i < 2; i++)
            __builtin_amdgcn_global_load_lds(AS1(Bg + k0 + i * 8 * Kd), AS3(BsW + i * 512), 16, 0, 0);
        __syncthreads();
#pragma unroll
        for (int h = 0; h < 2; h++) {
            const int c16 = (((h * 4 + quad) ^ cswz)) * 8;
            bf16x8 af[4], bfr[2];
#pragma unroll
            for (int i = 0; i < 4; i++)
                af[i] = *(const bf16x8*)(As + (size_t)(wm + i * 16 + lanelo) * 64 + c16);
#pragma unroll
            for (int j = 0; j < 2; j++)
                bfr[j] = *(const bf16x8*)(Bs + (size_t)(wn + j * 16 + lanelo) * 64 + c16);
#pragma unroll
            for (int i = 0; i < 4; i++)
#pragma unroll
                for (int j = 0; j < 2; j++)
                    acc[i][j] = __builtin_amdgcn_mfma_f32_16x16x32_bf16(af[i], bfr[j], acc[i][j], 0, 0, 0);
        }
    }

#pragma unroll
    for (int i = 0; i < 4; i++)
#pragma unroll
        for (int j = 0; j < 2; j++)
#pragma unroll
            for (int reg = 0; reg < 4; reg++) {
                const int row = m0 + wm + i * 16 + quad * 4 + reg;  // m = b*1024+t
                const int col = n0 + wn + j * 16 + lanelo;
                const int b = row >> 10, t = row & 1023;
                out[(size_t)(t * 4 + b) * 1024 + col] = acc[i][j][reg];
            }
}

// ---------------------------------------------------------------------------
// Flash attention (r13 measured best, 185.0 us total): paired q-supertiles
// (TB=15-px big + TS=px small in one k-loop — perfect load balance), staged
// K/V with DOUBLE-BUFFER Ks[2]/Vs[2] (79.9 KB LDS, 2 blocks/CU, ONE barrier
// per tile), XCD-aligned grid (64,8) (bh=blockIdx.x -> XCD=bh%8, K/V L2-homed,
// FETCH 68->15 MB measured r10), Wo cast prologue, T5 setprio. Flash ledger:
// no-staging(r11 --), Pband-global(r9 -), unpaired(r15 -), dbuf(r13 ~+0.5).
// ---------------------------------------------------------------------------
__global__ __launch_bounds__(256) void flash_attn(
    const __hip_bfloat16* __restrict__ Qb,
    const __hip_bfloat16* __restrict__ Kb,
    const __hip_bfloat16* __restrict__ Vtb,
    const float* __restrict__ P,
    const float* __restrict__ Wo,
    __hip_bfloat16* __restrict__ Wob,
    __hip_bfloat16* __restrict__ av) {
    __shared__ __hip_bfloat16 Ks[2][64][72];        // K tiles  [buf][klocal][d]
    __shared__ __hip_bfloat16 Vs[2][64][72];        // V' tiles [buf][d][klocal]
    __shared__ __hip_bfloat16 Pl[4][16][68];        // per-wave P tile (reused by both q-tiles)
    __shared__ __hip_bfloat16 Pband[4][2][16][68];  // per-wave, per-q-tile band
    __shared__ __hip_bfloat16 QPl[4][2][16][66];    // per-wave, per-q-tile Q.P[idx] (log2-scaled)

    const int px = blockIdx.y;        // 0..7  (XCD-aligned relabel, r10)
    const int TB = 15 - px, TS = px;  // big / small supertiles
    const int bh = blockIdx.x;        // 0..63 -> XCD = bh%8
    const int b = bh >> 4, h = bh & 15;
    const int tid = threadIdx.x;

    // Wo cast prologue (for out_gemm; bijective over the 512-block grid)
    {
        const int gid = (bh * 8 + px) * 256 + tid;   // 0..131071
        const float4 a = *(const float4*)(Wo + (size_t)gid * 8);
        const float4 c = *(const float4*)(Wo + (size_t)gid * 8 + 4);
        __hip_bfloat16 t[8];
        t[0] = __float2bfloat16(a.x); t[1] = __float2bfloat16(a.y);
        t[2] = __float2bfloat16(a.z); t[3] = __float2bfloat16(a.w);
        t[4] = __float2bfloat16(c.x); t[5] = __float2bfloat16(c.y);
        t[6] = __float2bfloat16(c.z); t[7] = __float2bfloat16(c.w);
        *(uint4*)(Wob + (size_t)gid * 8) = *(const uint4*)t;
    }

    const int w = tid >> 6, lane = tid & 63;
    const int lanelo = lane & 15, quad = lane >> 4;
    const size_t qkbase = (size_t)bh * 1024 * 64;
    const size_t vbase  = (size_t)bh * 64 * 1024;

    // staging coordinates: thread stages row sr, element cols sc..sc+15
    const int sr = tid >> 2;
    const int sc = (tid & 3) << 4;
    const __hip_bfloat16* kgb = Kb + qkbase + (size_t)sr * 64 + sc;    // +kt*4096
    const __hip_bfloat16* vgb = Vtb + vbase + (size_t)sr * 1024 + sc;  // +kt*64

    // zero this wave's bands
    {
        short* pb = (short*)&Pband[w][0][0][0];
        for (int i = lane; i < 2 * 16 * 68; i += 64) pb[i] = 0;
    }

    // Q A-fragments for both q-tiles
    bf16x8 aqb0, aqb1, aqs0, aqs1;
    {
        const __hip_bfloat16* qrb = Qb + qkbase + (size_t)(TB * 64 + w * 16 + lanelo) * 64;
        aqb0 = *(const bf16x8*)(qrb + quad * 8);
        aqb1 = *(const bf16x8*)(qrb + 32 + quad * 8);
        const __hip_bfloat16* qrs = Qb + qkbase + (size_t)(TS * 64 + w * 16 + lanelo) * 64;
        aqs0 = *(const bf16x8*)(qrs + quad * 8);
        aqs1 = *(const bf16x8*)(qrs + 32 + quad * 8);
    }

    // QP[t][row][i] = Q[row].P[i] via MFMA (Q already log2e-scaled)
#pragma unroll
    for (int jj = 0; jj < 5; jj++) {
        const float* prow = P + (size_t)(jj * 16 + lanelo) * 64 + quad * 8;
        float4 pa = *(const float4*)prow;
        float4 pb = *(const float4*)(prow + 4);
        float4 pc = *(const float4*)(prow + 32);
        float4 pd = *(const float4*)(prow + 36);
        __hip_bfloat16 t0[8], t1[8];
        t0[0] = __float2bfloat16(pa.x); t0[1] = __float2bfloat16(pa.y);
        t0[2] = __float2bfloat16(pa.z); t0[3] = __float2bfloat16(pa.w);
        t0[4] = __float2bfloat16(pb.x); t0[5] = __float2bfloat16(pb.y);
        t0[6] = __float2bfloat16(pb.z); t0[7] = __float2bfloat16(pb.w);
        t1[0] = __float2bfloat16(pc.x); t1[1] = __float2bfloat16(pc.y);
        t1[2] = __float2bfloat16(pc.z); t1[3] = __float2bfloat16(pc.w);
        t1[4] = __float2bfloat16(pd.x); t1[5] = __float2bfloat16(pd.y);
        t1[6] = __float2bfloat16(pd.z); t1[7] = __float2bfloat16(pd.w);
        f32x4 accB = (f32x4){0.f, 0.f, 0.f, 0.f};
        accB = __builtin_amdgcn_mfma_f32_16x16x32_bf16(aqb0, *(const bf16x8*)t0, accB, 0, 0, 0);
        accB = __builtin_amdgcn_mfma_f32_16x16x32_bf16(aqb1, *(const bf16x8*)t1, accB, 0, 0, 0);
        f32x4 accS = (f32x4){0.f, 0.f, 0.f, 0.f};
        accS = __builtin_amdgcn_mfma_f32_16x16x32_bf16(aqs0, *(const bf16x8*)t0, accS, 0, 0, 0);
        accS = __builtin_amdgcn_mfma_f32_16x16x32_bf16(aqs1, *(const bf16x8*)t1, accS, 0, 0, 0);
#pragma unroll
        for (int reg = 0; reg < 4; reg++) {
            QPl[w][0][quad * 4 + reg][jj * 16 + lanelo] = __float2bfloat16(accB[reg]);
            QPl[w][1][quad * 4 + reg][jj * 16 + lanelo] = __float2bfloat16(accS[reg]);
        }
    }
    float qp0b[4], qp0s[4];
#pragma unroll
    for (int reg = 0; reg < 4; reg++) {
        qp0b[reg] = (float)QPl[w][0][quad * 4 + reg][0];
        qp0s[reg] = (float)QPl[w][1][quad * 4 + reg][0];
    }

    f32x4 o_accB[4], o_lB, o_accS[4], o_lS;
#pragma unroll
    for (int dt = 0; dt < 4; dt++) {
        o_accB[dt] = (f32x4){0.f, 0.f, 0.f, 0.f};
        o_accS[dt] = (f32x4){0.f, 0.f, 0.f, 0.f};
    }
    o_lB = (f32x4){0.f, 0.f, 0.f, 0.f};
    o_lS = (f32x4){0.f, 0.f, 0.f, 0.f};
    const short one_bf = 0x3F80;
    const bf16x8 vones = {one_bf, one_bf, one_bf, one_bf, one_bf, one_bf, one_bf, one_bf};

    // per-q-tile score+softmax+PV against the staged tile in buf
    auto do_qtile = [&](int tq, int Tq, const bf16x8& a0, const bf16x8& a1,
                        const float* qp0, f32x4* o_acc, f32x4& o_l, int kt, int buf) {
        // S = Q @ K^T
        f32x4 s_acc[4];
        __builtin_amdgcn_s_setprio(1);
#pragma unroll
        for (int ct = 0; ct < 4; ct++) {
            bf16x8 b0 = *(const bf16x8*)&Ks[buf][ct * 16 + lanelo][quad * 8];
            bf16x8 b1 = *(const bf16x8*)&Ks[buf][ct * 16 + lanelo][32 + quad * 8];
            f32x4 acc = (f32x4){0.f, 0.f, 0.f, 0.f};
            acc = __builtin_amdgcn_mfma_f32_16x16x32_bf16(a0, b0, acc, 0, 0, 0);
            acc = __builtin_amdgcn_mfma_f32_16x16x32_bf16(a1, b1, acc, 0, 0, 0);
            s_acc[ct] = acc;
        }
        __builtin_amdgcn_s_setprio(0);
        const int q0 = Tq * 64 + w * 16;
        const int obase = q0 - kt * 64;
        if (kt < Tq - 1) {
            // far tile: uniform qp0, no mask
#pragma unroll
            for (int ct = 0; ct < 4; ct++)
#pragma unroll
                for (int reg = 0; reg < 4; reg++) {
                    const float p = __builtin_exp2f(s_acc[ct][reg] + qp0[reg]);
                    Pl[w][quad * 4 + reg][ct * 16 + lanelo] = __float2bfloat16(p);
                }
        } else {
            // near tile: per-element rel idx, mask, band capture
#pragma unroll
            for (int ct = 0; ct < 4; ct++)
#pragma unroll
                for (int reg = 0; reg < 4; reg++) {
                    const int rloc = quad * 4 + reg;
                    const int kl = ct * 16 + lanelo;
                    const int o = obase + rloc - kl;
                    const int idx = (o >= 64 || o < 0) ? 0 : (64 - o);
                    const float add = (float)QPl[w][tq][rloc][idx];
                    const float p = (o < 0) ? 0.f : __builtin_exp2f(s_acc[ct][reg] + add);
                    const __hip_bfloat16 pbv = __float2bfloat16(p);
                    Pl[w][rloc][kl] = pbv;
                    if (o >= 0 && o <= 63) Pband[w][tq][rloc][63 - o] = pbv;
                }
        }
        // O += P @ V' ; l += P @ 1
        __builtin_amdgcn_s_setprio(1);
#pragma unroll
        for (int c = 0; c < 2; c++) {
            bf16x8 ap = ld8(&Pl[w][lanelo][c * 32 + quad * 8]);
#pragma unroll
            for (int dt = 0; dt < 4; dt++) {
                bf16x8 bv = *(const bf16x8*)&Vs[buf][dt * 16 + lanelo][c * 32 + quad * 8];
                o_acc[dt] = __builtin_amdgcn_mfma_f32_16x16x32_bf16(ap, bv, o_acc[dt], 0, 0, 0);
            }
            o_l = __builtin_amdgcn_mfma_f32_16x16x32_bf16(ap, vones, o_l, 0, 0, 0);
        }
        __builtin_amdgcn_s_setprio(0);
    };

    // prologue: stage tile 0 into buf 0; prefetch tile 1 into regs
    uint4 rk0, rk1, rv0, rv1;
    rk0 = *(const uint4*)(kgb);
    rk1 = *(const uint4*)(kgb + 8);
    rv0 = *(const uint4*)(vgb);
    rv1 = *(const uint4*)(vgb + 8);
    *(uint4*)&Ks[0][sr][sc]     = rk0;
    *(uint4*)&Ks[0][sr][sc + 8] = rk1;
    *(uint4*)&Vs[0][sr][sc]     = rv0;
    *(uint4*)&Vs[0][sr][sc + 8] = rv1;
    if (TB >= 1) {
        rk0 = *(const uint4*)(kgb + 4096);
        rk1 = *(const uint4*)(kgb + 4096 + 8);
        rv0 = *(const uint4*)(vgb + 64);
        rv1 = *(const uint4*)(vgb + 64 + 8);
    }
    __syncthreads();   // buf0 staged

    for (int kt = 0; kt <= TB; kt++) {
        const int cur = kt & 1;
        if (kt < TB) {
            // stage next tile into the other buffer (overwrites tile kt-1,
            // whose readers finished before the end-of-iter-(kt-1) barrier)
            *(uint4*)&Ks[cur ^ 1][sr][sc]     = rk0;
            *(uint4*)&Ks[cur ^ 1][sr][sc + 8] = rk1;
            *(uint4*)&Vs[cur ^ 1][sr][sc]     = rv0;
            *(uint4*)&Vs[cur ^ 1][sr][sc + 8] = rv1;
            if (kt + 1 < TB) {   // prefetch tile kt+2 (latency spans compute)
                const __hip_bfloat16* kg = kgb + (size_t)(kt + 2) * 4096;
                const __hip_bfloat16* vg = vgb + (size_t)(kt + 2) * 64;
                rk0 = *(const uint4*)(kg);
                rk1 = *(const uint4*)(kg + 8);
                rv0 = *(const uint4*)(vg);
                rv1 = *(const uint4*)(vg + 8);
            }
        }

        do_qtile(0, TB, aqb0, aqb1, qp0b, o_accB, o_lB, kt, cur);
        if (kt <= TS) do_qtile(1, TS, aqs0, aqs1, qp0s, o_accS, o_lS, kt, cur);

        __syncthreads();   // readers of buf[cur] done; buf[cur^1] staged
    }

    // epilogue per q-tile: band correction + normalize + store
#pragma unroll
    for (int tq = 0; tq < 2; tq++) {
        f32x4* o_acc = tq == 0 ? o_accB : o_accS;
        f32x4& o_l   = tq == 0 ? o_lB : o_lS;
        const int q0 = (tq == 0 ? TB : TS) * 64 + w * 16;
#pragma unroll
        for (int c = 0; c < 2; c++) {
            bf16x8 ab = ld8(&Pband[w][tq][lanelo][c * 32 + quad * 8]);
#pragma unroll
            for (int dt = 0; dt < 4; dt++) {
                const int d = dt * 16 + lanelo;
                const float p0 = P[d];
                __hip_bfloat16 tb[8];
#pragma unroll
                for (int jj = 0; jj < 8; jj++) {
                    const int kk = c * 32 + quad * 8 + jj;
                    tb[jj] = __float2bfloat16(P[(kk + 1) * 64 + d] - p0);
                }
                o_acc[dt] = __builtin_amdgcn_mfma_f32_16x16x32_bf16(ab, *(const bf16x8*)tb, o_acc[dt], 0, 0, 0);
            }
        }
        float rinv[4];
#pragma unroll
        for (int reg = 0; reg < 4; reg++) rinv[reg] = 1.0f / o_l[reg];
#pragma unroll
        for (int dt = 0; dt < 4; dt++) {
            const int cdim = dt * 16 + lanelo;
#pragma unroll
            for (int reg = 0; reg < 4; reg++) {
                const int q = q0 + quad * 4 + reg;
                av[((size_t)(b * 1024 + q)) * 1024 + h * 64 + cdim] =
                    __float2bfloat16(o_acc[dt][reg] * rinv[reg]);
            }
        }
    }
}

extern "C" void kernel_launch(void* const* d_in, const int* in_sizes, int n_in,
                              void* d_out, int out_size, void* d_ws, size_t ws_size,
                              hipStream_t stream) {
    const float* w       = (const float*)d_in[0];
    // d_in[1] = attn_mask (deterministic causal; recomputed from indices)
    const float* Wqkv    = (const float*)d_in[2];
    const float* pos_emb = (const float*)d_in[3];
    const float* Wo      = (const float*)d_in[4];
    float* out = (float*)d_out;

    const size_t SZ = (size_t)BATCH * N_HEAD * T_SEQ * D_HEAD;  // 4,194,304
    __hip_bfloat16* wb     = (__hip_bfloat16*)d_ws;
    __hip_bfloat16* Wqkvb  = wb + SZ;
    __hip_bfloat16* Wob    = Wqkvb + 3 * 1024 * 1024;
    __hip_bfloat16* Qb     = Wob + 1024 * 1024;
    __hip_bfloat16* Kb     = Qb + SZ;
    __hip_bfloat16* Vtb    = Kb + SZ;
    __hip_bfloat16* AVb    = Vtb + SZ;

    const int n_w = 4096 * 1024, n_wqkv = 3072 * 1024;
    const int n_tot = n_w + n_wqkv;
    cast_all<<<n_tot / 2048, 256, 0, stream>>>(w, wb, n_w, Wqkv, Wqkvb, n_wqkv);

    qkv_gemm_mfma<<<dim3(3072 / 128, 4096 / 128), 256, 0, stream>>>(wb, Wqkvb, pos_emb, Qb, Kb, Vtb);
    // grid (64,8): bh = blockIdx.x (fast dim) -> XCD = bh%8; K/V L2-homed
    flash_attn<<<dim3(64, 8), 256, 0, stream>>>(Qb, Kb, Vtb, pos_emb, Wo, Wob, AVb);
    // grid (32,16): m-panel fast dim -> XCD = (m0/128)%8; A L2-homed (3 MB/XCD)
    out_gemm_mfma<<<dim3(4096 / 128, 1024 / 64), 256, 0, stream>>>(AVb, Wob, out);
}

// Round 18
// 178.110 us; speedup vs baseline: 1.0797x; 1.0346x over previous
//
#include <hip/hip_runtime.h>
#include <hip/hip_bf16.h>
#include <math.h>

#define N_HEAD 16
#define D_HEAD 64
#define T_SEQ 1024
#define BATCH 4
// 1/sqrt(64) * log2(e): Q pre-scaled so scores are in log2 units (exp2 softmax)
#define QSCALE 0.180336879f

typedef float f32x4 __attribute__((ext_vector_type(4)));
typedef short bf16x8 __attribute__((ext_vector_type(8)));
typedef short bf16x4v __attribute__((ext_vector_type(4)));

#define AS1(p) ((const __attribute__((address_space(1))) void*)(p))
#define AS3(p) ((__attribute__((address_space(3))) void*)(p))

// load 8 consecutive bf16 from LDS that are only 8B-aligned (stride 68/72)
__device__ inline bf16x8 ld8(const __hip_bfloat16* p) {
    bf16x4v lo = *(const bf16x4v*)p;
    bf16x4v hi = *(const bf16x4v*)(p + 4);
    return __builtin_shufflevector(lo, hi, 0, 1, 2, 3, 4, 5, 6, 7);
}

// ---------------------------------------------------------------------------
// fused fp32 -> bf16 cast of w, Wqkv (Wo cast folded into flash_attn)
// ---------------------------------------------------------------------------
__global__ __launch_bounds__(256) void cast_all(
    const float* __restrict__ s0, __hip_bfloat16* __restrict__ d0, int n0,
    const float* __restrict__ s1, __hip_bfloat16* __restrict__ d1, int n1) {
    int i = (blockIdx.x * 256 + threadIdx.x) * 8;
    const float* src;
    __hip_bfloat16* dst;
    if (i < n0) { src = s0 + i; dst = d0 + i; }
    else if ((i -= n0) < n1) { src = s1 + i; dst = d1 + i; }
    else return;
    float4 a = *(const float4*)src;
    float4 b = *(const float4*)(src + 4);
    __hip_bfloat16 t[8];
    t[0] = __float2bfloat16(a.x); t[1] = __float2bfloat16(a.y);
    t[2] = __float2bfloat16(a.z); t[3] = __float2bfloat16(a.w);
    t[4] = __float2bfloat16(b.x); t[5] = __float2bfloat16(b.y);
    t[6] = __float2bfloat16(b.z); t[7] = __float2bfloat16(b.w);
    *(uint4*)dst = *(const uint4*)t;
}

// ---------------------------------------------------------------------------
// QKV GEMM (m97 structure, 128x128, BK=32 — proven form, ~45 us). K-loop
// CLOSED after 6 probes (r1-r4, r8). R18: the V-transposed EPILOGUE write
// was a full 2B scatter (lanes stride 2KB, regs stride 2MB — every store
// its own cache line, ~32x line amplification). Fix: per-wave LDS transpose
// reusing dead As/Bs ([64][17]-padded slab/wave, part==2 blocks only):
// write sub-tile (+P[d] folded), read columns, store 16-lane runs of
// consecutive t = 32B contiguous transactions (16x fewer lines).
// Epilogue: Q scaled by (1/8)*log2e, K plain (both already coalesced).
// ---------------------------------------------------------------------------
__global__ __launch_bounds__(256) void qkv_gemm_mfma(
    const __hip_bfloat16* __restrict__ A,   // wb   [4096][1024], row m = t*4+b
    const __hip_bfloat16* __restrict__ B,   // Wqkv [3072][1024]
    const float* __restrict__ P,            // pos_emb [129][64]
    __hip_bfloat16* __restrict__ Qb, __hip_bfloat16* __restrict__ Kb,
    __hip_bfloat16* __restrict__ Vtb) {
    constexpr int Kd = 1024;
    __shared__ __hip_bfloat16 As[128 * 32];
    __shared__ __hip_bfloat16 Bs[128 * 32];
    const int tid = threadIdx.x;
    const int w = tid >> 6, lane = tid & 63;
    const int lanelo = lane & 15, quad = lane >> 4;
    const int wm = (w >> 1) * 64, wn = (w & 1) * 64;
    const int m0 = blockIdx.y * 128, n0 = blockIdx.x * 128;

    const __hip_bfloat16* Ag = A + (size_t)(m0 + w * 16 + (lane >> 2)) * Kd + (lane & 3) * 8;
    const __hip_bfloat16* Bg = B + (size_t)(n0 + w * 16 + (lane >> 2)) * Kd + (lane & 3) * 8;
    __hip_bfloat16* AsW0 = As + w * 16 * 32;
    __hip_bfloat16* AsW1 = As + (64 + w * 16) * 32;
    __hip_bfloat16* BsW0 = Bs + w * 16 * 32;
    __hip_bfloat16* BsW1 = Bs + (64 + w * 16) * 32;

    f32x4 acc[4][4];
#pragma unroll
    for (int i = 0; i < 4; i++)
#pragma unroll
        for (int j = 0; j < 4; j++) acc[i][j] = (f32x4){0.f, 0.f, 0.f, 0.f};

    for (int k0 = 0; k0 < Kd; k0 += 32) {
        __syncthreads();
        __builtin_amdgcn_global_load_lds(AS1(Ag + k0), AS3(AsW0), 16, 0, 0);
        __builtin_amdgcn_global_load_lds(AS1(Ag + 64 * Kd + k0), AS3(AsW1), 16, 0, 0);
        __builtin_amdgcn_global_load_lds(AS1(Bg + k0), AS3(BsW0), 16, 0, 0);
        __builtin_amdgcn_global_load_lds(AS1(Bg + 64 * Kd + k0), AS3(BsW1), 16, 0, 0);
        __syncthreads();
        bf16x8 af[4], bfr[4];
#pragma unroll
        for (int i = 0; i < 4; i++)
            af[i] = *(const bf16x8*)(As + (wm + i * 16 + lanelo) * 32 + quad * 8);
#pragma unroll
        for (int j = 0; j < 4; j++)
            bfr[j] = *(const bf16x8*)(Bs + (wn + j * 16 + lanelo) * 32 + quad * 8);
#pragma unroll
        for (int i = 0; i < 4; i++)
#pragma unroll
            for (int j = 0; j < 4; j++)
                acc[i][j] = __builtin_amdgcn_mfma_f32_16x16x32_bf16(af[i], bfr[j], acc[i][j], 0, 0, 0);
    }

    const int part = n0 >> 10;   // block-uniform: 0=q, 1=k, 2=v
    if (part != 2) {
#pragma unroll
        for (int i = 0; i < 4; i++)
#pragma unroll
            for (int j = 0; j < 4; j++)
#pragma unroll
                for (int reg = 0; reg < 4; reg++) {
                    const int row = m0 + wm + i * 16 + quad * 4 + reg;  // m = t*4+b
                    const int col = n0 + wn + j * 16 + lanelo;
                    const int t = row >> 2, b = row & 3;
                    const int e = col & 1023, h = e >> 6, d = e & 63;
                    const float v = acc[i][j][reg];
                    if (part == 0)
                        Qb[((size_t)(b * 16 + h) * 1024 + t) * 64 + d] = __float2bfloat16(v * QSCALE);
                    else
                        Kb[((size_t)(b * 16 + h) * 1024 + t) * 64 + d] = __float2bfloat16(v);
                }
    } else {
        // V: per-wave LDS transpose for coalesced writes. Old path was a 2B
        // scatter (lanes: d stride 2KB, regs: b stride 2MB). New: stage the
        // wave's 64x16 sub-tile (j-loop) in a private [64][17] slab (waves
        // 0/1 in As, 2/3 in Bs; 2176B each), then lane (g,tl) reads column
        // c2 and stores a 16-lane run of consecutive t (32B contiguous).
        float p0v[4];
#pragma unroll
        for (int j = 0; j < 4; j++) p0v[j] = P[j * 16 + lanelo];

        __hip_bfloat16* S = (w < 2 ? As : Bs) + (w & 1) * 1088;   // 64*17 elems
        const int h0 = ((n0 + wn) >> 6) & 15;    // n0+wn multiple of 64
        const int t0 = (m0 + wm) >> 2;           // m0+wm multiple of 64
        const int g = lane >> 4;                 // bb group 0..3
        const int tl = lane & 15;                // t offset within run
        // per-thread output base: Vtb[(g*16+h0)*64 * 1024 + ... + t0+tl]
        __hip_bfloat16* vout = Vtb + ((size_t)(g * 16 + h0) * 64) * 1024 + t0 + tl;

        for (int j = 0; j < 4; j++) {
            __syncthreads();   // j=0: waves done reading As/Bs (k-loop); j>0: slab reuse
#pragma unroll
            for (int i = 0; i < 4; i++)
#pragma unroll
                for (int reg = 0; reg < 4; reg++)
                    S[(i * 16 + quad * 4 + reg) * 17 + lanelo] =
                        __float2bfloat16(acc[i][j][reg] + p0v[j]);
            __syncthreads();   // slab populated (also orders LDS within wave)
#pragma unroll
            for (int c2 = 0; c2 < 16; c2++) {
                const __hip_bfloat16 v = S[(tl * 4 + g) * 17 + c2];
                vout[(size_t)(j * 16 + c2) * 1024] = v;
            }
        }
    }
}

// ---------------------------------------------------------------------------
// GEMM2: out[t,b,n] = sum_e AVb[b*1024+t][e] * Wob[n][e], fp32 out.
// 128x64 tile, BK=64, 24 KB LDS, 512 blocks (2/CU), r2 XOR swizzle.
// XCD-HOMED grid (r17, -0.7 us): launched (32,16) with m0 = blockIdx.x*128
// (fast dim) so XCD = (m0/128)%8: each XCD owns 4 A-panels (1 MB) x all
// Wob (2 MB) = 3 MB < 4 MB L2; A reused 16x from L2.
// ---------------------------------------------------------------------------
__global__ __launch_bounds__(256) void out_gemm_mfma(
    const __hip_bfloat16* __restrict__ A,
    const __hip_bfloat16* __restrict__ B,
    float* __restrict__ out) {
    constexpr int Kd = 1024;
    __shared__ __hip_bfloat16 As[128 * 64];
    __shared__ __hip_bfloat16 Bs[64 * 64];
    const int tid = threadIdx.x;
    const int w = tid >> 6, lane = tid & 63;
    const int lanelo = lane & 15, quad = lane >> 4;
    const int wm = (w >> 1) * 64, wn = (w & 1) * 32;
    const int m0 = blockIdx.x * 128, n0 = blockIdx.y * 64;   // XCD = (m0/128)%8

    const int sr = lane >> 3;                        // 0..7
    const int sc = ((lane & 7) ^ sr) * 8;            // swizzled k-col (elems)
    const __hip_bfloat16* Ag = A + (size_t)(m0 + w * 32 + sr) * Kd + sc;   // 4 instrs
    const __hip_bfloat16* Bg = B + (size_t)(n0 + w * 16 + sr) * Kd + sc;   // 2 instrs
    __hip_bfloat16* AsW = As + w * 2048;             // w*32 rows * 64
    __hip_bfloat16* BsW = Bs + w * 1024;             // w*16 rows * 64

    f32x4 acc[4][2];
#pragma unroll
    for (int i = 0; i < 4; i++)
#pragma unroll
        for (int j = 0; j < 2; j++) acc[i][j] = (f32x4){0.f, 0.f, 0.f, 0.f};

    const int cswz = lanelo & 7;

    for (int k0 = 0; k0 < Kd; k0 += 64) {
        __syncthreads();
#pragma unroll
        for (int i = 0; i < 4; i++)
            __builtin_amdgcn_global_load_lds(AS1(Ag + k0 + i * 8 * Kd), AS3(AsW + i * 512), 16, 0, 0);
#pragma unroll
        for (int i = 0; i < 2; i++)
            __builtin_amdgcn_global_load_lds(AS1(Bg + k0 + i * 8 * Kd), AS3(BsW + i * 512), 16, 0, 0);
        __syncthreads();
#pragma unroll
        for (int h = 0; h < 2; h++) {
            const int c16 = (((h * 4 + quad) ^ cswz)) * 8;
            bf16x8 af[4], bfr[2];
#pragma unroll
            for (int i = 0; i < 4; i++)
                af[i] = *(const bf16x8*)(As + (size_t)(wm + i * 16 + lanelo) * 64 + c16);
#pragma unroll
            for (int j = 0; j < 2; j++)
                bfr[j] = *(const bf16x8*)(Bs + (size_t)(wn + j * 16 + lanelo) * 64 + c16);
#pragma unroll
            for (int i = 0; i < 4; i++)
#pragma unroll
                for (int j = 0; j < 2; j++)
                    acc[i][j] = __builtin_amdgcn_mfma_f32_16x16x32_bf16(af[i], bfr[j], acc[i][j], 0, 0, 0);
        }
    }

#pragma unroll
    for (int i = 0; i < 4; i++)
#pragma unroll
        for (int j = 0; j < 2; j++)
#pragma unroll
            for (int reg = 0; reg < 4; reg++) {
                const int row = m0 + wm + i * 16 + quad * 4 + reg;  // m = b*1024+t
                const int col = n0 + wn + j * 16 + lanelo;
                const int b = row >> 10, t = row & 1023;
                out[(size_t)(t * 4 + b) * 1024 + col] = acc[i][j][reg];
            }
}

// ---------------------------------------------------------------------------
// Flash attention (r13 measured best): paired q-supertiles (TB=15-px big +
// TS=px small in one k-loop — perfect load balance), staged K/V with
// DOUBLE-BUFFER Ks[2]/Vs[2] (79.9 KB LDS, 2 blocks/CU, ONE barrier per
// tile), XCD-aligned grid (64,8) (bh=blockIdx.x -> XCD=bh%8, K/V L2-homed,
// FETCH 68->15 MB measured r10), Wo cast prologue, T5 setprio. Flash ledger:
// no-staging(r11 --), Pband-global(r9 -), unpaired(r15 -), dbuf(r13 ~+0.5).
// ---------------------------------------------------------------------------
__global__ __launch_bounds__(256) void flash_attn(
    const __hip_bfloat16* __restrict__ Qb,
    const __hip_bfloat16* __restrict__ Kb,
    const __hip_bfloat16* __restrict__ Vtb,
    const float* __restrict__ P,
    const float* __restrict__ Wo,
    __hip_bfloat16* __restrict__ Wob,
    __hip_bfloat16* __restrict__ av) {
    __shared__ __hip_bfloat16 Ks[2][64][72];        // K tiles  [buf][klocal][d]
    __shared__ __hip_bfloat16 Vs[2][64][72];        // V' tiles [buf][d][klocal]
    __shared__ __hip_bfloat16 Pl[4][16][68];        // per-wave P tile (reused by both q-tiles)
    __shared__ __hip_bfloat16 Pband[4][2][16][68];  // per-wave, per-q-tile band
    __shared__ __hip_bfloat16 QPl[4][2][16][66];    // per-wave, per-q-tile Q.P[idx] (log2-scaled)

    const int px = blockIdx.y;        // 0..7  (XCD-aligned relabel, r10)
    const int TB = 15 - px, TS = px;  // big / small supertiles
    const int bh = blockIdx.x;        // 0..63 -> XCD = bh%8
    const int b = bh >> 4, h = bh & 15;
    const int tid = threadIdx.x;

    // Wo cast prologue (for out_gemm; bijective over the 512-block grid)
    {
        const int gid = (bh * 8 + px) * 256 + tid;   // 0..131071
        const float4 a = *(const float4*)(Wo + (size_t)gid * 8);
        const float4 c = *(const float4*)(Wo + (size_t)gid * 8 + 4);
        __hip_bfloat16 t[8];
        t[0] = __float2bfloat16(a.x); t[1] = __float2bfloat16(a.y);
        t[2] = __float2bfloat16(a.z); t[3] = __float2bfloat16(a.w);
        t[4] = __float2bfloat16(c.x); t[5] = __float2bfloat16(c.y);
        t[6] = __float2bfloat16(c.z); t[7] = __float2bfloat16(c.w);
        *(uint4*)(Wob + (size_t)gid * 8) = *(const uint4*)t;
    }

    const int w = tid >> 6, lane = tid & 63;
    const int lanelo = lane & 15, quad = lane >> 4;
    const size_t qkbase = (size_t)bh * 1024 * 64;
    const size_t vbase  = (size_t)bh * 64 * 1024;

    // staging coordinates: thread stages row sr, element cols sc..sc+15
    const int sr = tid >> 2;
    const int sc = (tid & 3) << 4;
    const __hip_bfloat16* kgb = Kb + qkbase + (size_t)sr * 64 + sc;    // +kt*4096
    const __hip_bfloat16* vgb = Vtb + vbase + (size_t)sr * 1024 + sc;  // +kt*64

    // zero this wave's bands
    {
        short* pb = (short*)&Pband[w][0][0][0];
        for (int i = lane; i < 2 * 16 * 68; i += 64) pb[i] = 0;
    }

    // Q A-fragments for both q-tiles
    bf16x8 aqb0, aqb1, aqs0, aqs1;
    {
        const __hip_bfloat16* qrb = Qb + qkbase + (size_t)(TB * 64 + w * 16 + lanelo) * 64;
        aqb0 = *(const bf16x8*)(qrb + quad * 8);
        aqb1 = *(const bf16x8*)(qrb + 32 + quad * 8);
        const __hip_bfloat16* qrs = Qb + qkbase + (size_t)(TS * 64 + w * 16 + lanelo) * 64;
        aqs0 = *(const bf16x8*)(qrs + quad * 8);
        aqs1 = *(const bf16x8*)(qrs + 32 + quad * 8);
    }

    // QP[t][row][i] = Q[row].P[i] via MFMA (Q already log2e-scaled)
#pragma unroll
    for (int jj = 0; jj < 5; jj++) {
        const float* prow = P + (size_t)(jj * 16 + lanelo) * 64 + quad * 8;
        float4 pa = *(const float4*)prow;
        float4 pb = *(const float4*)(prow + 4);
        float4 pc = *(const float4*)(prow + 32);
        float4 pd = *(const float4*)(prow + 36);
        __hip_bfloat16 t0[8], t1[8];
        t0[0] = __float2bfloat16(pa.x); t0[1] = __float2bfloat16(pa.y);
        t0[2] = __float2bfloat16(pa.z); t0[3] = __float2bfloat16(pa.w);
        t0[4] = __float2bfloat16(pb.x); t0[5] = __float2bfloat16(pb.y);
        t0[6] = __float2bfloat16(pb.z); t0[7] = __float2bfloat16(pb.w);
        t1[0] = __float2bfloat16(pc.x); t1[1] = __float2bfloat16(pc.y);
        t1[2] = __float2bfloat16(pc.z); t1[3] = __float2bfloat16(pc.w);
        t1[4] = __float2bfloat16(pd.x); t1[5] = __float2bfloat16(pd.y);
        t1[6] = __float2bfloat16(pd.z); t1[7] = __float2bfloat16(pd.w);
        f32x4 accB = (f32x4){0.f, 0.f, 0.f, 0.f};
        accB = __builtin_amdgcn_mfma_f32_16x16x32_bf16(aqb0, *(const bf16x8*)t0, accB, 0, 0, 0);
        accB = __builtin_amdgcn_mfma_f32_16x16x32_bf16(aqb1, *(const bf16x8*)t1, accB, 0, 0, 0);
        f32x4 accS = (f32x4){0.f, 0.f, 0.f, 0.f};
        accS = __builtin_amdgcn_mfma_f32_16x16x32_bf16(aqs0, *(const bf16x8*)t0, accS, 0, 0, 0);
        accS = __builtin_amdgcn_mfma_f32_16x16x32_bf16(aqs1, *(const bf16x8*)t1, accS, 0, 0, 0);
#pragma unroll
        for (int reg = 0; reg < 4; reg++) {
            QPl[w][0][quad * 4 + reg][jj * 16 + lanelo] = __float2bfloat16(accB[reg]);
            QPl[w][1][quad * 4 + reg][jj * 16 + lanelo] = __float2bfloat16(accS[reg]);
        }
    }
    float qp0b[4], qp0s[4];
#pragma unroll
    for (int reg = 0; reg < 4; reg++) {
        qp0b[reg] = (float)QPl[w][0][quad * 4 + reg][0];
        qp0s[reg] = (float)QPl[w][1][quad * 4 + reg][0];
    }

    f32x4 o_accB[4], o_lB, o_accS[4], o_lS;
#pragma unroll
    for (int dt = 0; dt < 4; dt++) {
        o_accB[dt] = (f32x4){0.f, 0.f, 0.f, 0.f};
        o_accS[dt] = (f32x4){0.f, 0.f, 0.f, 0.f};
    }
    o_lB = (f32x4){0.f, 0.f, 0.f, 0.f};
    o_lS = (f32x4){0.f, 0.f, 0.f, 0.f};
    const short one_bf = 0x3F80;
    const bf16x8 vones = {one_bf, one_bf, one_bf, one_bf, one_bf, one_bf, one_bf, one_bf};

    // per-q-tile score+softmax+PV against the staged tile in buf
    auto do_qtile = [&](int tq, int Tq, const bf16x8& a0, const bf16x8& a1,
                        const float* qp0, f32x4* o_acc, f32x4& o_l, int kt, int buf) {
        // S = Q @ K^T
        f32x4 s_acc[4];
        __builtin_amdgcn_s_setprio(1);
#pragma unroll
        for (int ct = 0; ct < 4; ct++) {
            bf16x8 b0 = *(const bf16x8*)&Ks[buf][ct * 16 + lanelo][quad * 8];
            bf16x8 b1 = *(const bf16x8*)&Ks[buf][ct * 16 + lanelo][32 + quad * 8];
            f32x4 acc = (f32x4){0.f, 0.f, 0.f, 0.f};
            acc = __builtin_amdgcn_mfma_f32_16x16x32_bf16(a0, b0, acc, 0, 0, 0);
            acc = __builtin_amdgcn_mfma_f32_16x16x32_bf16(a1, b1, acc, 0, 0, 0);
            s_acc[ct] = acc;
        }
        __builtin_amdgcn_s_setprio(0);
        const int q0 = Tq * 64 + w * 16;
        const int obase = q0 - kt * 64;
        if (kt < Tq - 1) {
            // far tile: uniform qp0, no mask
#pragma unroll
            for (int ct = 0; ct < 4; ct++)
#pragma unroll
                for (int reg = 0; reg < 4; reg++) {
                    const float p = __builtin_exp2f(s_acc[ct][reg] + qp0[reg]);
                    Pl[w][quad * 4 + reg][ct * 16 + lanelo] = __float2bfloat16(p);
                }
        } else {
            // near tile: per-element rel idx, mask, band capture
#pragma unroll
            for (int ct = 0; ct < 4; ct++)
#pragma unroll
                for (int reg = 0; reg < 4; reg++) {
                    const int rloc = quad * 4 + reg;
                    const int kl = ct * 16 + lanelo;
                    const int o = obase + rloc - kl;
                    const int idx = (o >= 64 || o < 0) ? 0 : (64 - o);
                    const float add = (float)QPl[w][tq][rloc][idx];
                    const float p = (o < 0) ? 0.f : __builtin_exp2f(s_acc[ct][reg] + add);
                    const __hip_bfloat16 pbv = __float2bfloat16(p);
                    Pl[w][rloc][kl] = pbv;
                    if (o >= 0 && o <= 63) Pband[w][tq][rloc][63 - o] = pbv;
                }
        }
        // O += P @ V' ; l += P @ 1
        __builtin_amdgcn_s_setprio(1);
#pragma unroll
        for (int c = 0; c < 2; c++) {
            bf16x8 ap = ld8(&Pl[w][lanelo][c * 32 + quad * 8]);
#pragma unroll
            for (int dt = 0; dt < 4; dt++) {
                bf16x8 bv = *(const bf16x8*)&Vs[buf][dt * 16 + lanelo][c * 32 + quad * 8];
                o_acc[dt] = __builtin_amdgcn_mfma_f32_16x16x32_bf16(ap, bv, o_acc[dt], 0, 0, 0);
            }
            o_l = __builtin_amdgcn_mfma_f32_16x16x32_bf16(ap, vones, o_l, 0, 0, 0);
        }
        __builtin_amdgcn_s_setprio(0);
    };

    // prologue: stage tile 0 into buf 0; prefetch tile 1 into regs
    uint4 rk0, rk1, rv0, rv1;
    rk0 = *(const uint4*)(kgb);
    rk1 = *(const uint4*)(kgb + 8);
    rv0 = *(const uint4*)(vgb);
    rv1 = *(const uint4*)(vgb + 8);
    *(uint4*)&Ks[0][sr][sc]     = rk0;
    *(uint4*)&Ks[0][sr][sc + 8] = rk1;
    *(uint4*)&Vs[0][sr][sc]     = rv0;
    *(uint4*)&Vs[0][sr][sc + 8] = rv1;
    if (TB >= 1) {
        rk0 = *(const uint4*)(kgb + 4096);
        rk1 = *(const uint4*)(kgb + 4096 + 8);
        rv0 = *(const uint4*)(vgb + 64);
        rv1 = *(const uint4*)(vgb + 64 + 8);
    }
    __syncthreads();   // buf0 staged

    for (int kt = 0; kt <= TB; kt++) {
        const int cur = kt & 1;
        if (kt < TB) {
            // stage next tile into the other buffer (overwrites tile kt-1,
            // whose readers finished before the end-of-iter-(kt-1) barrier)
            *(uint4*)&Ks[cur ^ 1][sr][sc]     = rk0;
            *(uint4*)&Ks[cur ^ 1][sr][sc + 8] = rk1;
            *(uint4*)&Vs[cur ^ 1][sr][sc]     = rv0;
            *(uint4*)&Vs[cur ^ 1][sr][sc + 8] = rv1;
            if (kt + 1 < TB) {   // prefetch tile kt+2 (latency spans compute)
                const __hip_bfloat16* kg = kgb + (size_t)(kt + 2) * 4096;
                const __hip_bfloat16* vg = vgb + (size_t)(kt + 2) * 64;
                rk0 = *(const uint4*)(kg);
                rk1 = *(const uint4*)(kg + 8);
                rv0 = *(const uint4*)(vg);
                rv1 = *(const uint4*)(vg + 8);
            }
        }

        do_qtile(0, TB, aqb0, aqb1, qp0b, o_accB, o_lB, kt, cur);
        if (kt <= TS) do_qtile(1, TS, aqs0, aqs1, qp0s, o_accS, o_lS, kt, cur);

        __syncthreads();   // readers of buf[cur] done; buf[cur^1] staged
    }

    // epilogue per q-tile: band correction + normalize + store
#pragma unroll
    for (int tq = 0; tq < 2; tq++) {
        f32x4* o_acc = tq == 0 ? o_accB : o_accS;
        f32x4& o_l   = tq == 0 ? o_lB : o_lS;
        const int q0 = (tq == 0 ? TB : TS) * 64 + w * 16;
#pragma unroll
        for (int c = 0; c < 2; c++) {
            bf16x8 ab = ld8(&Pband[w][tq][lanelo][c * 32 + quad * 8]);
#pragma unroll
            for (int dt = 0; dt < 4; dt++) {
                const int d = dt * 16 + lanelo;
                const float p0 = P[d];
                __hip_bfloat16 tb[8];
#pragma unroll
                for (int jj = 0; jj < 8; jj++) {
                    const int kk = c * 32 + quad * 8 + jj;
                    tb[jj] = __float2bfloat16(P[(kk + 1) * 64 + d] - p0);
                }
                o_acc[dt] = __builtin_amdgcn_mfma_f32_16x16x32_bf16(ab, *(const bf16x8*)tb, o_acc[dt], 0, 0, 0);
            }
        }
        float rinv[4];
#pragma unroll
        for (int reg = 0; reg < 4; reg++) rinv[reg] = 1.0f / o_l[reg];
#pragma unroll
        for (int dt = 0; dt < 4; dt++) {
            const int cdim = dt * 16 + lanelo;
#pragma unroll
            for (int reg = 0; reg < 4; reg++) {
                const int q = q0 + quad * 4 + reg;
                av[((size_t)(b * 1024 + q)) * 1024 + h * 64 + cdim] =
                    __float2bfloat16(o_acc[dt][reg] * rinv[reg]);
            }
        }
    }
}

extern "C" void kernel_launch(void* const* d_in, const int* in_sizes, int n_in,
                              void* d_out, int out_size, void* d_ws, size_t ws_size,
                              hipStream_t stream) {
    const float* w       = (const float*)d_in[0];
    // d_in[1] = attn_mask (deterministic causal; recomputed from indices)
    const float* Wqkv    = (const float*)d_in[2];
    const float* pos_emb = (const float*)d_in[3];
    const float* Wo      = (const float*)d_in[4];
    float* out = (float*)d_out;

    const size_t SZ = (size_t)BATCH * N_HEAD * T_SEQ * D_HEAD;  // 4,194,304
    __hip_bfloat16* wb     = (__hip_bfloat16*)d_ws;
    __hip_bfloat16* Wqkvb  = wb + SZ;
    __hip_bfloat16* Wob    = Wqkvb + 3 * 1024 * 1024;
    __hip_bfloat16* Qb     = Wob + 1024 * 1024;
    __hip_bfloat16* Kb     = Qb + SZ;
    __hip_bfloat16* Vtb    = Kb + SZ;
    __hip_bfloat16* AVb    = Vtb + SZ;

    const int n_w = 4096 * 1024, n_wqkv = 3072 * 1024;
    const int n_tot = n_w + n_wqkv;
    cast_all<<<n_tot / 2048, 256, 0, stream>>>(w, wb, n_w, Wqkv, Wqkvb, n_wqkv);

    qkv_gemm_mfma<<<dim3(3072 / 128, 4096 / 128), 256, 0, stream>>>(wb, Wqkvb, pos_emb, Qb, Kb, Vtb);
    // grid (64,8): bh = blockIdx.x (fast dim) -> XCD = bh%8; K/V L2-homed
    flash_attn<<<dim3(64, 8), 256, 0, stream>>>(Qb, Kb, Vtb, pos_emb, Wo, Wob, AVb);
    // grid (32,16): m-panel fast dim -> XCD = (m0/128)%8; A L2-homed (3 MB/XCD)
    out_gemm_mfma<<<dim3(4096 / 128, 1024 / 64), 256, 0, stream>>>(AVb, Wob, out);
}